// Round 1
// baseline (1367.741 us; speedup 1.0000x reference)
//
#include <hip/hip_runtime.h>
#include <hip/hip_bf16.h>
#include <cstddef>

// Problem constants
#define Bb 2
#define Cc_ 8
#define BINS 1024
#define Ww 512
#define HEADS 8
#define HD 128
#define ROT 64
#define NELEM (Bb*Cc_*BINS*Ww)   // 8388608

// ---------------------------------------------------------------------------
// Kernel 1/5: per-channel linear  Y[bc][o][w] = sum_i A[c][o][i] * X[bc][i][w]
// A: [C][1024][1024] row-major, X/Y: [B*C][1024][512]
// Tiled f32: BM=BN=64, BK=16, 256 threads, 4x4 micro-tile.
// ---------------------------------------------------------------------------
__global__ void __launch_bounds__(256) mc_matmul(const float* __restrict__ W,
                                                 const float* __restrict__ X,
                                                 float* __restrict__ Y) {
    int bc = blockIdx.z;
    int c  = bc & 7;
    const float* A  = W + (size_t)c  * BINS * BINS;
    const float* Bm = X + (size_t)bc * BINS * Ww;
    float*       Cm = Y + (size_t)bc * BINS * Ww;
    int m0 = blockIdx.y * 64;
    int n0 = blockIdx.x * 64;

    __shared__ float As[16][68];   // [k][m], stride 68: 16B-aligned rows, 2-way max conflict
    __shared__ float Bs[16][68];   // [k][n]

    int t  = threadIdx.x;
    int ty = t >> 4, tx = t & 15;      // rows 4ty..4ty+3, cols 4tx..4tx+3
    int ar = t >> 2, ak = (t & 3) * 4; // A tile load: float4 per thread
    int br = t >> 6, bcol = t & 63;    // B tile load

    float acc[4][4] = {};

    for (int k0 = 0; k0 < BINS; k0 += 16) {
        float4 av = *(const float4*)&A[(size_t)(m0 + ar) * BINS + k0 + ak];
        As[ak + 0][ar] = av.x; As[ak + 1][ar] = av.y;
        As[ak + 2][ar] = av.z; As[ak + 3][ar] = av.w;
        #pragma unroll
        for (int i = 0; i < 4; i++)
            Bs[br + 4 * i][bcol] = Bm[(size_t)(k0 + br + 4 * i) * Ww + n0 + bcol];
        __syncthreads();
        #pragma unroll
        for (int k = 0; k < 16; k++) {
            float a4[4], b4[4];
            #pragma unroll
            for (int i = 0; i < 4; i++) a4[i] = As[k][4 * ty + i];
            #pragma unroll
            for (int i = 0; i < 4; i++) b4[i] = Bs[k][4 * tx + i];
            #pragma unroll
            for (int a = 0; a < 4; a++)
                #pragma unroll
                for (int b = 0; b < 4; b++) acc[a][b] += a4[a] * b4[b];
        }
        __syncthreads();
    }
    #pragma unroll
    for (int a = 0; a < 4; a++) {
        float4 v = make_float4(acc[a][0], acc[a][1], acc[a][2], acc[a][3]);
        *(float4*)&Cm[(size_t)(m0 + 4 * ty + a) * Ww + n0 + 4 * tx] = v;
    }
}

// ---------------------------------------------------------------------------
// Kernel 2/5: cross-channel 1x3 conv + bias.
// qp[b][co][h][w] = bias[co] + sum_{ci,kw} y[b][ci][h][w+kw-1] * Wc[co][ci][0][kw]
// One block per (h, b); 256 threads over w.
// ---------------------------------------------------------------------------
__global__ void __launch_bounds__(256) conv1x3(const float* __restrict__ y,
                                               const float* __restrict__ Wc,
                                               const float* __restrict__ bias,
                                               float* __restrict__ qp) {
    int h = blockIdx.x, b = blockIdx.y;
    __shared__ float ys[8][514];     // padded by 1 on each side (zero)
    __shared__ float wgt[192];       // [co][ci][kw]
    __shared__ float bs[8];
    int t = threadIdx.x;
    if (t < 192) wgt[t] = Wc[t];
    if (t < 8) { bs[t] = bias[t]; ys[t][0] = 0.f; ys[t][513] = 0.f; }
    for (int i = t; i < 8 * 512; i += 256) {
        int ci = i >> 9, w = i & 511;
        ys[ci][w + 1] = y[((size_t)(b * 8 + ci) * BINS + h) * Ww + w];
    }
    __syncthreads();
    for (int w = t; w < 512; w += 256) {
        #pragma unroll
        for (int co = 0; co < 8; co++) {
            float s = bs[co];
            #pragma unroll
            for (int ci = 0; ci < 8; ci++) {
                const float* wp = &wgt[(co * 8 + ci) * 3];
                s += ys[ci][w + 0] * wp[0] + ys[ci][w + 1] * wp[1] + ys[ci][w + 2] * wp[2];
            }
            qp[((size_t)(b * 8 + co) * BINS + h) * Ww + w] = s;
        }
    }
}

// ---------------------------------------------------------------------------
// Kernel 3/5: rotary + transpose to [bch][p][d] layout; also emit v (un-rotated).
// qh[bch][p][d] = qp[bc][h*128+d][p]
// ---------------------------------------------------------------------------
__global__ void rotary_transpose(const float* __restrict__ qp,
                                 float* __restrict__ qrot,
                                 float* __restrict__ vbuf) {
    int p = blockIdx.x, bch = blockIdx.y;
    int d = threadIdx.x;                 // 0..127
    int bc = bch >> 3, h0 = bch & 7;
    float val = qp[((size_t)bc * BINS + h0 * HD + d) * Ww + p];
    float out = val;
    if (d < ROT) {
        float partner = __shfl_xor(val, 1);
        int j = d >> 1;
        // inv = 10000^(-2j/64)
        float inv = expf(-(2.0f * j / 64.0f) * 9.210340371976184f);
        float theta = (float)p * inv;
        float sn, cs;
        sincosf(theta, &sn, &cs);
        out = (d & 1) ? (val * cs + partner * sn)   // odd:  x2*cos + x1*sin
                      : (val * cs - partner * sn);  // even: x1*cos - x2*sin
    }
    size_t o = ((size_t)bch * Ww + p) * HD + d;
    qrot[o] = out;
    vbuf[o] = val;
}

// ---------------------------------------------------------------------------
// Kernel 4/5: attention per (bch), flash-style. Q tile = 32 rows, K/V tile = 64.
// Writes output directly in [bc][bin][p] layout for the final linear.
// ---------------------------------------------------------------------------
__global__ void __launch_bounds__(256) attn_kernel(const float* __restrict__ qrot,
                                                   const float* __restrict__ vbuf,
                                                   float* __restrict__ aout) {
    int bch = blockIdx.y;
    int q0  = blockIdx.x * 32;
    int t   = threadIdx.x;
    int ty  = t >> 4;   // rows 2ty, 2ty+1 (of 32)
    int tx  = t & 15;   // S cols 4tx..4tx+3 (of 64); O cols 8tx..8tx+7 (of 128)

    __shared__ float Qs[32][129];
    __shared__ float KVs[64][129];
    __shared__ float Ps[32][65];
    __shared__ float mbuf[32], lbuf[32], abuf[32];

    const float* qb = qrot + (size_t)bch * Ww * HD;
    const float* vb = vbuf + (size_t)bch * Ww * HD;
    const float scale = 0.03125f;   // 1/sqrt(1024)

    for (int i = 0; i < 16; i++) {
        int idx = t + i * 256;
        int r = idx >> 7, d = idx & 127;
        Qs[r][d] = qb[(size_t)(q0 + r) * HD + d];
    }
    if (t < 32) { mbuf[t] = -1e30f; lbuf[t] = 0.f; }

    float o[2][8];
    #pragma unroll
    for (int a = 0; a < 2; a++)
        #pragma unroll
        for (int b = 0; b < 8; b++) o[a][b] = 0.f;

    for (int kt = 0; kt < 8; kt++) {
        int k0 = kt * 64;
        __syncthreads();   // previous PV done; KVs/Ps free (also covers Q load on iter 0)
        for (int i = 0; i < 32; i++) {
            int idx = t + i * 256;
            int r = idx >> 7, d = idx & 127;
            KVs[r][d] = qb[(size_t)(k0 + r) * HD + d];
        }
        __syncthreads();
        // S micro-tile: 2 q-rows x 4 k-cols, dot over d=128
        float s[2][4] = {};
        for (int d = 0; d < 128; d++) {
            float qv0 = Qs[2 * ty][d], qv1 = Qs[2 * ty + 1][d];
            #pragma unroll
            for (int b = 0; b < 4; b++) {
                float kv = KVs[4 * tx + b][d];
                s[0][b] += qv0 * kv;
                s[1][b] += qv1 * kv;
            }
        }
        #pragma unroll
        for (int a = 0; a < 2; a++)
            #pragma unroll
            for (int b = 0; b < 4; b++)
                Ps[2 * ty + a][4 * tx + b] = s[a][b] * scale;
        __syncthreads();   // S complete -> KVs free, Ps complete
        // load V tile (all threads), row-softmax (first 32 threads after their loads)
        for (int i = 0; i < 32; i++) {
            int idx = t + i * 256;
            int r = idx >> 7, d = idx & 127;
            KVs[r][d] = vb[(size_t)(k0 + r) * HD + d];
        }
        if (t < 32) {
            int r = t;
            float mold = mbuf[r];
            float tmax = -1e30f;
            for (int k = 0; k < 64; k++) tmax = fmaxf(tmax, Ps[r][k]);
            float mnew = fmaxf(mold, tmax);
            float alpha = __expf(mold - mnew);
            float sum = 0.f;
            for (int k = 0; k < 64; k++) {
                float p = __expf(Ps[r][k] - mnew);
                Ps[r][k] = p;
                sum += p;
            }
            lbuf[r] = lbuf[r] * alpha + sum;
            mbuf[r] = mnew;
            abuf[r] = alpha;
        }
        __syncthreads();
        // rescale O, accumulate PV
        float al0 = abuf[2 * ty], al1 = abuf[2 * ty + 1];
        #pragma unroll
        for (int b = 0; b < 8; b++) { o[0][b] *= al0; o[1][b] *= al1; }
        for (int kk = 0; kk < 64; kk++) {
            float p0 = Ps[2 * ty][kk], p1 = Ps[2 * ty + 1][kk];
            #pragma unroll
            for (int b = 0; b < 8; b++) {
                float vv = KVs[kk][8 * tx + b];
                o[0][b] += p0 * vv;
                o[1][b] += p1 * vv;
            }
        }
    }
    // epilogue: normalize and write in [bc][h*128+d][p] layout
    int bc = bch >> 3, h0 = bch & 7;
    float linv0 = 1.f / lbuf[2 * ty], linv1 = 1.f / lbuf[2 * ty + 1];
    #pragma unroll
    for (int b = 0; b < 8; b++) {
        int d = 8 * tx + b;
        size_t base = ((size_t)bc * BINS + h0 * HD + d) * Ww;
        aout[base + q0 + 2 * ty]     = o[0][b] * linv0;
        aout[base + q0 + 2 * ty + 1] = o[1][b] * linv1;
    }
}

// ---------------------------------------------------------------------------
// Launch
// ---------------------------------------------------------------------------
extern "C" void kernel_launch(void* const* d_in, const int* in_sizes, int n_in,
                              void* d_out, int out_size, void* d_ws, size_t ws_size,
                              hipStream_t stream) {
    const float* x       = (const float*)d_in[0];
    const float* Wq_lin  = (const float*)d_in[1];
    const float* Wq_conv = (const float*)d_in[2];
    const float* bq_conv = (const float*)d_in[3];
    const float* Wout    = (const float*)d_in[4];
    float* out = (float*)d_out;

    float* bufA = (float*)d_ws;          // y, then qrot
    float* bufB = bufA + NELEM;          // qp, then attention out
    float* bufC = bufB + NELEM;          // vbuf

    // 1. y = Wq_lin @ x   (per channel)
    mc_matmul<<<dim3(Ww / 64, BINS / 64, Bb * Cc_), 256, 0, stream>>>(Wq_lin, x, bufA);
    // 2. qp = conv1x3(y) + bias
    conv1x3<<<dim3(BINS, Bb), 256, 0, stream>>>(bufA, Wq_conv, bq_conv, bufB);
    // 3. rotary + transpose: qrot (bufA), v (bufC)
    rotary_transpose<<<dim3(Ww, Bb * Cc_ * HEADS), HD, 0, stream>>>(bufB, bufA, bufC);
    // 4. attention -> bufB in [bc][bin][p] layout
    attn_kernel<<<dim3(Ww / 32, Bb * Cc_ * HEADS), 256, 0, stream>>>(bufA, bufC, bufB);
    // 5. out = Wout @ attn
    mc_matmul<<<dim3(Ww / 64, BINS / 64, Bb * Cc_), 256, 0, stream>>>(Wout, bufB, out);
}

// Round 2
// 684.903 us; speedup vs baseline: 1.9970x; 1.9970x over previous
//
#include <hip/hip_runtime.h>
#include <cstddef>

// Problem constants
#define Bb 2
#define Cc_ 8
#define BINS 1024
#define Ww 512
#define HEADS 8
#define HD 128
#define ROT 64
#define NELEM (Bb*Cc_*BINS*Ww)   // 8388608

typedef __attribute__((ext_vector_type(8))) __bf16 bf16x8;
typedef __attribute__((ext_vector_type(4))) float  f32x4;
#define MFMA16(a,b,c) __builtin_amdgcn_mfma_f32_16x16x32_bf16(a,b,c,0,0,0)

// ---------------------------------------------------------------------------
// Kernel 1/5: per-channel linear  Y[bc][o][w] = sum_i A[c][o][i] * X[bc][i][w]
// (unchanged f32 from R1 — converted to MFMA next round)
// ---------------------------------------------------------------------------
__global__ void __launch_bounds__(256) mc_matmul(const float* __restrict__ W,
                                                 const float* __restrict__ X,
                                                 float* __restrict__ Y) {
    int bc = blockIdx.z;
    int c  = bc & 7;
    const float* A  = W + (size_t)c  * BINS * BINS;
    const float* Bm = X + (size_t)bc * BINS * Ww;
    float*       Cm = Y + (size_t)bc * BINS * Ww;
    int m0 = blockIdx.y * 64;
    int n0 = blockIdx.x * 64;

    __shared__ float As[16][68];
    __shared__ float Bs[16][68];

    int t  = threadIdx.x;
    int ty = t >> 4, tx = t & 15;
    int ar = t >> 2, ak = (t & 3) * 4;
    int br = t >> 6, bcol = t & 63;

    float acc[4][4] = {};

    for (int k0 = 0; k0 < BINS; k0 += 16) {
        float4 av = *(const float4*)&A[(size_t)(m0 + ar) * BINS + k0 + ak];
        As[ak + 0][ar] = av.x; As[ak + 1][ar] = av.y;
        As[ak + 2][ar] = av.z; As[ak + 3][ar] = av.w;
        #pragma unroll
        for (int i = 0; i < 4; i++)
            Bs[br + 4 * i][bcol] = Bm[(size_t)(k0 + br + 4 * i) * Ww + n0 + bcol];
        __syncthreads();
        #pragma unroll
        for (int k = 0; k < 16; k++) {
            float a4[4], b4[4];
            #pragma unroll
            for (int i = 0; i < 4; i++) a4[i] = As[k][4 * ty + i];
            #pragma unroll
            for (int i = 0; i < 4; i++) b4[i] = Bs[k][4 * tx + i];
            #pragma unroll
            for (int a = 0; a < 4; a++)
                #pragma unroll
                for (int b = 0; b < 4; b++) acc[a][b] += a4[a] * b4[b];
        }
        __syncthreads();
    }
    #pragma unroll
    for (int a = 0; a < 4; a++) {
        float4 v = make_float4(acc[a][0], acc[a][1], acc[a][2], acc[a][3]);
        *(float4*)&Cm[(size_t)(m0 + 4 * ty + a) * Ww + n0 + 4 * tx] = v;
    }
}

// ---------------------------------------------------------------------------
// Kernel 2/5: cross-channel 1x3 conv + bias. Also emits bf16 copy of qp,
// which IS v-transposed ([bch][d][p]) for the attention kernel.
// ---------------------------------------------------------------------------
__global__ void __launch_bounds__(256) conv1x3(const float* __restrict__ y,
                                               const float* __restrict__ Wc,
                                               const float* __restrict__ bias,
                                               float* __restrict__ qp,
                                               __bf16* __restrict__ vt) {
    int h = blockIdx.x, b = blockIdx.y;
    __shared__ float ys[8][514];
    __shared__ float wgt[192];
    __shared__ float bs[8];
    int t = threadIdx.x;
    if (t < 192) wgt[t] = Wc[t];
    if (t < 8) { bs[t] = bias[t]; ys[t][0] = 0.f; ys[t][513] = 0.f; }
    for (int i = t; i < 8 * 512; i += 256) {
        int ci = i >> 9, w = i & 511;
        ys[ci][w + 1] = y[((size_t)(b * 8 + ci) * BINS + h) * Ww + w];
    }
    __syncthreads();
    for (int w = t; w < 512; w += 256) {
        #pragma unroll
        for (int co = 0; co < 8; co++) {
            float s = bs[co];
            #pragma unroll
            for (int ci = 0; ci < 8; ci++) {
                const float* wp = &wgt[(co * 8 + ci) * 3];
                s += ys[ci][w + 0] * wp[0] + ys[ci][w + 1] * wp[1] + ys[ci][w + 2] * wp[2];
            }
            size_t o = ((size_t)(b * 8 + co) * BINS + h) * Ww + w;
            qp[o] = s;
            vt[o] = (__bf16)s;
        }
    }
}

// ---------------------------------------------------------------------------
// Kernel 3/5: rotary + transpose to bf16 [bch][p][d], coalesced via LDS tile.
// Block: (p-tile of 64, bch). Pairs (even,odd) are adjacent in d, so no shuffle.
// ---------------------------------------------------------------------------
__global__ void __launch_bounds__(256) rotary_transpose(const float* __restrict__ qp,
                                                        __bf16* __restrict__ qrot) {
    int p0  = blockIdx.x * 64;
    int bch = blockIdx.y;
    int bc = bch >> 3, h0 = bch & 7;
    int t = threadIdx.x;
    __shared__ float T[64 * 129];   // [p_local][d]

    const float* src = qp + ((size_t)bc * BINS + h0 * HD) * Ww;
    // read: 128 d-rows x 64 p, coalesced float4 along p
    for (int pass = 0; pass < 8; pass++) {
        int idx = t + pass * 256;           // 0..2047
        int d = idx >> 4, chunk = idx & 15; // 16 x float4 per row
        float4 v = *(const float4*)&src[(size_t)d * Ww + p0 + chunk * 4];
        T[(chunk * 4 + 0) * 129 + d] = v.x;
        T[(chunk * 4 + 1) * 129 + d] = v.y;
        T[(chunk * 4 + 2) * 129 + d] = v.z;
        T[(chunk * 4 + 3) * 129 + d] = v.w;
    }
    __syncthreads();
    // write: 64 p-rows x 128 d, rotary on d<64, bf16x8 stores
    for (int pass = 0; pass < 4; pass++) {
        int idx = t + pass * 256;            // 0..1023
        int p = idx >> 4, chunk = idx & 15;  // 16 x 8 bf16 per row
        float pos = (float)(p0 + p);
        bf16x8 o;
        if (chunk < 8) {
            #pragma unroll
            for (int j = 0; j < 8; j += 2) {
                int d = chunk * 8 + j;
                int jj = d >> 1;
                float inv = __expf(-(2.0f * jj / 64.0f) * 9.210340371976184f);
                float sn, cs;
                __sincosf(pos * inv, &sn, &cs);
                float x1 = T[p * 129 + d];
                float x2 = T[p * 129 + d + 1];
                o[j]     = (__bf16)(x1 * cs - x2 * sn);
                o[j + 1] = (__bf16)(x2 * cs + x1 * sn);
            }
        } else {
            #pragma unroll
            for (int j = 0; j < 8; j++)
                o[j] = (__bf16)T[p * 129 + chunk * 8 + j];
        }
        *(bf16x8*)&qrot[((size_t)bch * Ww + p0 + p) * HD + chunk * 8] = o;
    }
}

// ---------------------------------------------------------------------------
// Kernel 4/5: MFMA flash attention. Block = (q-tile 64, bch), 4 waves.
// Wave w owns q-rows [w*16, w*16+16). K/V tile = 64. 16x16x32 bf16 MFMA.
// LDS rows padded so max aliasing is 2-way (free).
// ---------------------------------------------------------------------------
__global__ void __launch_bounds__(256) attn_mfma(const __bf16* __restrict__ qrot,
                                                 const __bf16* __restrict__ vt,
                                                 float* __restrict__ aout) {
    int bch = blockIdx.y;
    int q0  = blockIdx.x * 64;
    int t = threadIdx.x;
    int wv = t >> 6, lane = t & 63, quad = lane >> 4, l16 = lane & 15;

    __shared__ __align__(16) char smem[45056];
    __bf16* Ks  = (__bf16*)smem;             // 64 x 136  (Q staging, then K tiles)
    __bf16* Vts = (__bf16*)(smem + 17408);   // 128 x 72  (V^T tiles: [d][kpos])
    __bf16* Ps  = (__bf16*)(smem + 35840);   // 64 x 72   (P: [qrow][kpos])

    const __bf16* qb = qrot + (size_t)bch * Ww * HD;   // [p][d]
    const __bf16* vb = vt   + (size_t)bch * HD * Ww;   // [d][p]
    const float scale = 0.03125f;  // 1/sqrt(1024)

    // stage Q tile (reuse Ks region), pull A-frags to registers
    for (int pass = 0; pass < 4; pass++) {
        int idx = t + pass * 256;
        int r = idx >> 4, chunk = idx & 15;
        *(bf16x8*)&Ks[r * 136 + chunk * 8] =
            *(const bf16x8*)&qb[(size_t)(q0 + r) * HD + chunk * 8];
    }
    __syncthreads();
    bf16x8 aq[4];
    #pragma unroll
    for (int c = 0; c < 4; c++)
        aq[c] = *(bf16x8*)&Ks[(wv * 16 + l16) * 136 + c * 32 + quad * 8];

    f32x4 oacc[8];
    #pragma unroll
    for (int dt = 0; dt < 8; dt++) oacc[dt] = (f32x4){0.f, 0.f, 0.f, 0.f};
    float m_st[4], l_st[4];
    #pragma unroll
    for (int r = 0; r < 4; r++) { m_st[r] = -1e30f; l_st[r] = 0.f; }

    for (int kt = 0; kt < 8; kt++) {
        int k0 = kt * 64;
        __syncthreads();   // prior reads of Ks/Vts/Ps done
        for (int pass = 0; pass < 4; pass++) {          // K tile [kpos][d]
            int idx = t + pass * 256;
            int r = idx >> 4, chunk = idx & 15;
            *(bf16x8*)&Ks[r * 136 + chunk * 8] =
                *(const bf16x8*)&qb[(size_t)(k0 + r) * HD + chunk * 8];
        }
        for (int pass = 0; pass < 4; pass++) {          // V^T tile [d][kpos]
            int idx = t + pass * 256;
            int r = idx >> 3, chunk = idx & 7;
            *(bf16x8*)&Vts[r * 72 + chunk * 8] =
                *(const bf16x8*)&vb[(size_t)r * Ww + k0 + chunk * 8];
        }
        __syncthreads();

        // S = Q K^T : wave's 16 rows x 64 cols
        f32x4 s[4];
        #pragma unroll
        for (int nt = 0; nt < 4; nt++) {
            s[nt] = (f32x4){0.f, 0.f, 0.f, 0.f};
            #pragma unroll
            for (int c = 0; c < 4; c++) {
                bf16x8 bk = *(bf16x8*)&Ks[(nt * 16 + l16) * 136 + c * 32 + quad * 8];
                s[nt] = MFMA16(aq[c], bk, s[nt]);
            }
        }

        // online softmax (C layout: lane row = quad*4+r, col = l16 + 16*nt)
        float alpha[4];
        #pragma unroll
        for (int r = 0; r < 4; r++) {
            float tmax = -1e30f;
            #pragma unroll
            for (int nt = 0; nt < 4; nt++) tmax = fmaxf(tmax, s[nt][r]);
            #pragma unroll
            for (int off = 8; off; off >>= 1) tmax = fmaxf(tmax, __shfl_xor(tmax, off));
            float mnew = fmaxf(m_st[r], tmax * scale);
            alpha[r] = __expf(m_st[r] - mnew);
            float sum = 0.f;
            #pragma unroll
            for (int nt = 0; nt < 4; nt++) {
                float p = __expf(s[nt][r] * scale - mnew);
                s[nt][r] = p;
                sum += p;
            }
            #pragma unroll
            for (int off = 8; off; off >>= 1) sum += __shfl_xor(sum, off);
            l_st[r] = l_st[r] * alpha[r] + sum;
            m_st[r] = mnew;
        }
        // P -> bf16 LDS; rescale O
        #pragma unroll
        for (int r = 0; r < 4; r++) {
            int row = wv * 16 + quad * 4 + r;
            #pragma unroll
            for (int nt = 0; nt < 4; nt++)
                Ps[row * 72 + nt * 16 + l16] = (__bf16)s[nt][r];
        }
        #pragma unroll
        for (int dt = 0; dt < 8; dt++)
            #pragma unroll
            for (int r = 0; r < 4; r++) oacc[dt][r] *= alpha[r];
        __syncthreads();

        // O += P V  (A = P rows, B = V^T rows)
        #pragma unroll
        for (int kc = 0; kc < 2; kc++) {
            bf16x8 ap = *(bf16x8*)&Ps[(wv * 16 + l16) * 72 + kc * 32 + quad * 8];
            #pragma unroll
            for (int dt = 0; dt < 8; dt++) {
                bf16x8 bv = *(bf16x8*)&Vts[(dt * 16 + l16) * 72 + kc * 32 + quad * 8];
                oacc[dt] = MFMA16(ap, bv, oacc[dt]);
            }
        }
    }

    // epilogue: normalize, transpose via LDS, coalesced store to [bc][bin][p]
    __syncthreads();
    float* Osm = (float*)smem;   // 64 x 133
    float linv[4];
    #pragma unroll
    for (int r = 0; r < 4; r++) linv[r] = 1.f / l_st[r];
    #pragma unroll
    for (int dt = 0; dt < 8; dt++)
        #pragma unroll
        for (int r = 0; r < 4; r++)
            Osm[(wv * 16 + quad * 4 + r) * 133 + dt * 16 + l16] = oacc[dt][r] * linv[r];
    __syncthreads();
    int bc = bch >> 3, h0 = bch & 7;
    for (int i = 0; i < 32; i++) {
        int d = wv * 32 + i;
        aout[((size_t)(bc * BINS) + h0 * HD + d) * Ww + q0 + lane] = Osm[lane * 133 + d];
    }
}

// ---------------------------------------------------------------------------
// Launch
// ---------------------------------------------------------------------------
extern "C" void kernel_launch(void* const* d_in, const int* in_sizes, int n_in,
                              void* d_out, int out_size, void* d_ws, size_t ws_size,
                              hipStream_t stream) {
    const float* x       = (const float*)d_in[0];
    const float* Wq_lin  = (const float*)d_in[1];
    const float* Wq_conv = (const float*)d_in[2];
    const float* bq_conv = (const float*)d_in[3];
    const float* Wout    = (const float*)d_in[4];
    float* out = (float*)d_out;

    float*  bufA = (float*)d_ws;            // y, then attention out
    float*  bufB = bufA + NELEM;            // qp (f32)
    __bf16* qrot = (__bf16*)(bufB + NELEM); // rotated heads [bch][p][d]
    __bf16* vtb  = qrot + NELEM;            // v-transposed  [bch][d][p] (== bf16 qp)

    // 1. y = Wq_lin @ x
    mc_matmul<<<dim3(Ww / 64, BINS / 64, Bb * Cc_), 256, 0, stream>>>(Wq_lin, x, bufA);
    // 2. qp = conv1x3(y) + bias; also bf16 copy (= V^T layout)
    conv1x3<<<dim3(BINS, Bb), 256, 0, stream>>>(bufA, Wq_conv, bq_conv, bufB, vtb);
    // 3. rotary + transpose -> qrot bf16
    rotary_transpose<<<dim3(Ww / 64, Bb * Cc_ * HEADS), 256, 0, stream>>>(bufB, qrot);
    // 4. MFMA flash attention -> bufA in [bc][bin][p] f32
    attn_mfma<<<dim3(Ww / 64, Bb * Cc_ * HEADS), 256, 0, stream>>>(qrot, vtb, bufA);
    // 5. out = Wout @ attn
    mc_matmul<<<dim3(Ww / 64, BINS / 64, Bb * Cc_), 256, 0, stream>>>(Wout, bufA, out);
}

// Round 3
// 328.606 us; speedup vs baseline: 4.1622x; 2.0843x over previous
//
#include <hip/hip_runtime.h>
#include <cstddef>

// Problem constants
#define Bb 2
#define Cc_ 8
#define BINS 1024
#define Ww 512
#define HEADS 8
#define HD 128
#define ROT 64
#define NELEM (Bb*Cc_*BINS*Ww)   // 8388608

typedef __attribute__((ext_vector_type(8))) __bf16 bf16x8;
typedef __attribute__((ext_vector_type(4))) float  f32x4;
#define MFMA16(a,b,c) __builtin_amdgcn_mfma_f32_16x16x32_bf16(a,b,c,0,0,0)

// async global->LDS, 16B per lane. lds ptr must be wave-uniform; HW places
// lane i at ldsbase + i*16.
__device__ __forceinline__ void async16(const __bf16* g, __bf16* l) {
    __builtin_amdgcn_global_load_lds(
        (const __attribute__((address_space(1))) void*)g,
        (__attribute__((address_space(3))) void*)l, 16, 0, 0);
}

// ---------------------------------------------------------------------------
// Kernel: f32 -> bf16 elementwise cast (for W matrices). 8 elems/thread.
// ---------------------------------------------------------------------------
__global__ void __launch_bounds__(256) cast_bf16(const float* __restrict__ in,
                                                 __bf16* __restrict__ out) {
    size_t i = ((size_t)blockIdx.x * 256 + threadIdx.x) * 8;
    float4 a = *(const float4*)&in[i];
    float4 b = *(const float4*)&in[i + 4];
    bf16x8 o = {(__bf16)a.x, (__bf16)a.y, (__bf16)a.z, (__bf16)a.w,
                (__bf16)b.x, (__bf16)b.y, (__bf16)b.z, (__bf16)b.w};
    *(bf16x8*)&out[i] = o;
}

// ---------------------------------------------------------------------------
// Kernel: x [bc][i][w] f32  ->  xT [bc][w][i] bf16 (B^T layout for gemm_bt)
// 64x64 LDS tile transpose.
// ---------------------------------------------------------------------------
__global__ void __launch_bounds__(256) transpose_cast_x(const float* __restrict__ x,
                                                        __bf16* __restrict__ xT) {
    int w0 = blockIdx.x * 64, i0 = blockIdx.y * 64, bc = blockIdx.z;
    const float* src = x + (size_t)bc * BINS * Ww;
    __bf16* dst = xT + (size_t)bc * Ww * BINS;
    __shared__ float T[64][65];
    int t = threadIdx.x;
    #pragma unroll
    for (int pass = 0; pass < 4; pass++) {
        int idx = t + pass * 256;          // 0..1023
        int il = idx >> 4, ch = idx & 15;  // 16 x float4 per i-row
        float4 v = *(const float4*)&src[(size_t)(i0 + il) * Ww + w0 + ch * 4];
        T[il][ch * 4 + 0] = v.x; T[il][ch * 4 + 1] = v.y;
        T[il][ch * 4 + 2] = v.z; T[il][ch * 4 + 3] = v.w;
    }
    __syncthreads();
    #pragma unroll
    for (int pass = 0; pass < 2; pass++) {
        int idx = t + pass * 256;          // 0..511
        int wl = idx >> 3, ch = idx & 7;   // 8 x bf16x8 per w-row
        bf16x8 o;
        #pragma unroll
        for (int j = 0; j < 8; j++) o[j] = (__bf16)T[ch * 8 + j][wl];
        *(bf16x8*)&dst[(size_t)(w0 + wl) * BINS + i0 + ch * 8] = o;
    }
}

// ---------------------------------------------------------------------------
// Kernel: bf16 MFMA GEMM, m97 structure.
// Y[bc][m][n] = sum_k A[c][m][k] * Bt[bc][n][k]   (M=1024,N=512,K=1024)
// 128x128 tile, BK=32, 4 waves, 4x4 16x16x32 MFMA per wave, global_load_lds.
// ---------------------------------------------------------------------------
__global__ void __launch_bounds__(256) gemm_bt(const __bf16* __restrict__ Wall,
                                               const __bf16* __restrict__ Bt,
                                               float* __restrict__ Y) {
    int bc = blockIdx.z, c = bc & 7;
    const __bf16* A  = Wall + (size_t)c  * BINS * BINS;   // [m][k]
    const __bf16* Bm = Bt   + (size_t)bc * Ww * BINS;     // [n][k]
    float*        Cm = Y    + (size_t)bc * BINS * Ww;     // [m][n]
    int n0 = blockIdx.x * 128, m0 = blockIdx.y * 128;

    __shared__ __bf16 Asm[128 * 32];   // [row m][k] rows of 64B, no pad
    __shared__ __bf16 Bsm[128 * 32];   // [row n][k]

    int t = threadIdx.x, w = t >> 6, l = t & 63;
    int quad = l >> 4, l16 = l & 15;
    int wm = w >> 1, wn = w & 1;

    // staging map: chunk c = (w*2+j)*64 + l  ->  row c>>2, k-chunk c&3
    int rowS[2], kcS[2];
    #pragma unroll
    for (int j = 0; j < 2; j++) {
        int ch = (w * 2 + j) * 64 + l;
        rowS[j] = ch >> 2;
        kcS[j]  = (ch & 3) * 8;
    }

    f32x4 acc[4][4];
    #pragma unroll
    for (int a = 0; a < 4; a++)
        #pragma unroll
        for (int b = 0; b < 4; b++) acc[a][b] = (f32x4){0.f, 0.f, 0.f, 0.f};

    for (int k0 = 0; k0 < BINS; k0 += 32) {
        __syncthreads();   // prior iteration's ds_reads done
        #pragma unroll
        for (int j = 0; j < 2; j++) {
            async16(A  + (size_t)(m0 + rowS[j]) * BINS + k0 + kcS[j],
                    Asm + (w * 2 + j) * 512);
            async16(Bm + (size_t)(n0 + rowS[j]) * BINS + k0 + kcS[j],
                    Bsm + (w * 2 + j) * 512);
        }
        __syncthreads();   // loads drained (vmcnt(0) at barrier)
        bf16x8 af[4], bf[4];
        #pragma unroll
        for (int i = 0; i < 4; i++)
            af[i] = *(bf16x8*)&Asm[(wm * 64 + i * 16 + l16) * 32 + quad * 8];
        #pragma unroll
        for (int i = 0; i < 4; i++)
            bf[i] = *(bf16x8*)&Bsm[(wn * 64 + i * 16 + l16) * 32 + quad * 8];
        #pragma unroll
        for (int am = 0; am < 4; am++)
            #pragma unroll
            for (int bn = 0; bn < 4; bn++)
                acc[am][bn] = MFMA16(af[am], bf[bn], acc[am][bn]);
    }

    // C layout: row = quad*4 + r, col = l16
    #pragma unroll
    for (int am = 0; am < 4; am++)
        #pragma unroll
        for (int bn = 0; bn < 4; bn++)
            #pragma unroll
            for (int r = 0; r < 4; r++)
                Cm[(size_t)(m0 + wm * 64 + am * 16 + quad * 4 + r) * Ww
                   + n0 + wn * 64 + bn * 16 + l16] = acc[am][bn][r];
}

// ---------------------------------------------------------------------------
// Kernel: cross-channel 1x3 conv + bias. Emits qp f32 and bf16 copy (= V^T).
// ---------------------------------------------------------------------------
__global__ void __launch_bounds__(256) conv1x3(const float* __restrict__ y,
                                               const float* __restrict__ Wc,
                                               const float* __restrict__ bias,
                                               float* __restrict__ qp,
                                               __bf16* __restrict__ vt) {
    int h = blockIdx.x, b = blockIdx.y;
    __shared__ float ys[8][514];
    __shared__ float wgt[192];
    __shared__ float bs[8];
    int t = threadIdx.x;
    if (t < 192) wgt[t] = Wc[t];
    if (t < 8) { bs[t] = bias[t]; ys[t][0] = 0.f; ys[t][513] = 0.f; }
    for (int i = t; i < 8 * 512; i += 256) {
        int ci = i >> 9, w = i & 511;
        ys[ci][w + 1] = y[((size_t)(b * 8 + ci) * BINS + h) * Ww + w];
    }
    __syncthreads();
    for (int w = t; w < 512; w += 256) {
        #pragma unroll
        for (int co = 0; co < 8; co++) {
            float s = bs[co];
            #pragma unroll
            for (int ci = 0; ci < 8; ci++) {
                const float* wp = &wgt[(co * 8 + ci) * 3];
                s += ys[ci][w + 0] * wp[0] + ys[ci][w + 1] * wp[1] + ys[ci][w + 2] * wp[2];
            }
            size_t o = ((size_t)(b * 8 + co) * BINS + h) * Ww + w;
            qp[o] = s;
            vt[o] = (__bf16)s;
        }
    }
}

// ---------------------------------------------------------------------------
// Kernel: rotary + transpose to bf16 [bch][p][d], coalesced via LDS tile.
// ---------------------------------------------------------------------------
__global__ void __launch_bounds__(256) rotary_transpose(const float* __restrict__ qp,
                                                        __bf16* __restrict__ qrot) {
    int p0  = blockIdx.x * 64;
    int bch = blockIdx.y;
    int bc = bch >> 3, h0 = bch & 7;
    int t = threadIdx.x;
    __shared__ float T[64 * 129];   // [p_local][d]

    const float* src = qp + ((size_t)bc * BINS + h0 * HD) * Ww;
    for (int pass = 0; pass < 8; pass++) {
        int idx = t + pass * 256;
        int d = idx >> 4, chunk = idx & 15;
        float4 v = *(const float4*)&src[(size_t)d * Ww + p0 + chunk * 4];
        T[(chunk * 4 + 0) * 129 + d] = v.x;
        T[(chunk * 4 + 1) * 129 + d] = v.y;
        T[(chunk * 4 + 2) * 129 + d] = v.z;
        T[(chunk * 4 + 3) * 129 + d] = v.w;
    }
    __syncthreads();
    for (int pass = 0; pass < 4; pass++) {
        int idx = t + pass * 256;
        int p = idx >> 4, chunk = idx & 15;
        float pos = (float)(p0 + p);
        bf16x8 o;
        if (chunk < 8) {
            #pragma unroll
            for (int j = 0; j < 8; j += 2) {
                int d = chunk * 8 + j;
                int jj = d >> 1;
                float inv = __expf(-(2.0f * jj / 64.0f) * 9.210340371976184f);
                float sn, cs;
                __sincosf(pos * inv, &sn, &cs);
                float x1 = T[p * 129 + d];
                float x2 = T[p * 129 + d + 1];
                o[j]     = (__bf16)(x1 * cs - x2 * sn);
                o[j + 1] = (__bf16)(x2 * cs + x1 * sn);
            }
        } else {
            #pragma unroll
            for (int j = 0; j < 8; j++)
                o[j] = (__bf16)T[p * 129 + chunk * 8 + j];
        }
        *(bf16x8*)&qrot[((size_t)bch * Ww + p0 + p) * HD + chunk * 8] = o;
    }
}

// ---------------------------------------------------------------------------
// Kernel: MFMA flash attention. Output written bf16 in B^T layout
// attnT[bc][p][bin] — natural for attention, exactly what gemm_bt wants.
// ---------------------------------------------------------------------------
__global__ void __launch_bounds__(256) attn_mfma(const __bf16* __restrict__ qrot,
                                                 const __bf16* __restrict__ vt,
                                                 __bf16* __restrict__ attnT) {
    int bch = blockIdx.y;
    int q0  = blockIdx.x * 64;
    int t = threadIdx.x;
    int wv = t >> 6, lane = t & 63, quad = lane >> 4, l16 = lane & 15;

    __shared__ __align__(16) char smem[45056];
    __bf16* Ks  = (__bf16*)smem;             // 64 x 136
    __bf16* Vts = (__bf16*)(smem + 17408);   // 128 x 72
    __bf16* Ps  = (__bf16*)(smem + 35840);   // 64 x 72

    const __bf16* qb = qrot + (size_t)bch * Ww * HD;   // [p][d]
    const __bf16* vb = vt   + (size_t)bch * HD * Ww;   // [d][p]
    const float scale = 0.03125f;  // 1/sqrt(1024)

    for (int pass = 0; pass < 4; pass++) {
        int idx = t + pass * 256;
        int r = idx >> 4, chunk = idx & 15;
        *(bf16x8*)&Ks[r * 136 + chunk * 8] =
            *(const bf16x8*)&qb[(size_t)(q0 + r) * HD + chunk * 8];
    }
    __syncthreads();
    bf16x8 aq[4];
    #pragma unroll
    for (int c = 0; c < 4; c++)
        aq[c] = *(bf16x8*)&Ks[(wv * 16 + l16) * 136 + c * 32 + quad * 8];

    f32x4 oacc[8];
    #pragma unroll
    for (int dt = 0; dt < 8; dt++) oacc[dt] = (f32x4){0.f, 0.f, 0.f, 0.f};
    float m_st[4], l_st[4];
    #pragma unroll
    for (int r = 0; r < 4; r++) { m_st[r] = -1e30f; l_st[r] = 0.f; }

    for (int kt = 0; kt < 8; kt++) {
        int k0 = kt * 64;
        __syncthreads();
        for (int pass = 0; pass < 4; pass++) {
            int idx = t + pass * 256;
            int r = idx >> 4, chunk = idx & 15;
            *(bf16x8*)&Ks[r * 136 + chunk * 8] =
                *(const bf16x8*)&qb[(size_t)(k0 + r) * HD + chunk * 8];
        }
        for (int pass = 0; pass < 4; pass++) {
            int idx = t + pass * 256;
            int r = idx >> 3, chunk = idx & 7;
            *(bf16x8*)&Vts[r * 72 + chunk * 8] =
                *(const bf16x8*)&vb[(size_t)r * Ww + k0 + chunk * 8];
        }
        __syncthreads();

        f32x4 s[4];
        #pragma unroll
        for (int nt = 0; nt < 4; nt++) {
            s[nt] = (f32x4){0.f, 0.f, 0.f, 0.f};
            #pragma unroll
            for (int c = 0; c < 4; c++) {
                bf16x8 bk = *(bf16x8*)&Ks[(nt * 16 + l16) * 136 + c * 32 + quad * 8];
                s[nt] = MFMA16(aq[c], bk, s[nt]);
            }
        }

        float alpha[4];
        #pragma unroll
        for (int r = 0; r < 4; r++) {
            float tmax = -1e30f;
            #pragma unroll
            for (int nt = 0; nt < 4; nt++) tmax = fmaxf(tmax, s[nt][r]);
            #pragma unroll
            for (int off = 8; off; off >>= 1) tmax = fmaxf(tmax, __shfl_xor(tmax, off));
            float mnew = fmaxf(m_st[r], tmax * scale);
            alpha[r] = __expf(m_st[r] - mnew);
            float sum = 0.f;
            #pragma unroll
            for (int nt = 0; nt < 4; nt++) {
                float p = __expf(s[nt][r] * scale - mnew);
                s[nt][r] = p;
                sum += p;
            }
            #pragma unroll
            for (int off = 8; off; off >>= 1) sum += __shfl_xor(sum, off);
            l_st[r] = l_st[r] * alpha[r] + sum;
            m_st[r] = mnew;
        }
        #pragma unroll
        for (int r = 0; r < 4; r++) {
            int row = wv * 16 + quad * 4 + r;
            #pragma unroll
            for (int nt = 0; nt < 4; nt++)
                Ps[row * 72 + nt * 16 + l16] = (__bf16)s[nt][r];
        }
        #pragma unroll
        for (int dt = 0; dt < 8; dt++)
            #pragma unroll
            for (int r = 0; r < 4; r++) oacc[dt][r] *= alpha[r];
        __syncthreads();

        #pragma unroll
        for (int kc = 0; kc < 2; kc++) {
            bf16x8 ap = *(bf16x8*)&Ps[(wv * 16 + l16) * 72 + kc * 32 + quad * 8];
            #pragma unroll
            for (int dt = 0; dt < 8; dt++) {
                bf16x8 bv = *(bf16x8*)&Vts[(dt * 16 + l16) * 72 + kc * 32 + quad * 8];
                oacc[dt] = MFMA16(ap, bv, oacc[dt]);
            }
        }
    }

    // epilogue: normalize -> bf16 LDS [p][d] -> coalesced 16B stores to
    // attnT[bc][q0+p][h0*HD + d]  (B^T layout for the final gemm)
    __syncthreads();
    __bf16* Obuf = (__bf16*)smem;   // 64 x 136
    float linv[4];
    #pragma unroll
    for (int r = 0; r < 4; r++) linv[r] = 1.f / l_st[r];
    #pragma unroll
    for (int dt = 0; dt < 8; dt++)
        #pragma unroll
        for (int r = 0; r < 4; r++)
            Obuf[(wv * 16 + quad * 4 + r) * 136 + dt * 16 + l16] =
                (__bf16)(oacc[dt][r] * linv[r]);
    __syncthreads();
    int bc = bch >> 3, h0 = bch & 7;
    for (int pass = 0; pass < 4; pass++) {
        int idx = t + pass * 256;
        int p = idx >> 4, chunk = idx & 15;
        *(bf16x8*)&attnT[((size_t)bc * Ww + q0 + p) * BINS + h0 * HD + chunk * 8] =
            *(bf16x8*)&Obuf[p * 136 + chunk * 8];
    }
}

// ---------------------------------------------------------------------------
// Launch. Workspace: 6 slots of NELEM bf16 = 100.66 MB (same as R1/R2).
//  U0 Wq_bf | U1 xT | U2 Wout_bf | U3+U4 y(f32) | U5 vt
//  then: qp(f32)->U0U1, qrot->U3, attnT->U4  (liveness-safe reuse)
// ---------------------------------------------------------------------------
extern "C" void kernel_launch(void* const* d_in, const int* in_sizes, int n_in,
                              void* d_out, int out_size, void* d_ws, size_t ws_size,
                              hipStream_t stream) {
    const float* x       = (const float*)d_in[0];
    const float* Wq_lin  = (const float*)d_in[1];
    const float* Wq_conv = (const float*)d_in[2];
    const float* bq_conv = (const float*)d_in[3];
    const float* Wout    = (const float*)d_in[4];
    float* out = (float*)d_out;

    __bf16* U = (__bf16*)d_ws;
    __bf16* Wq_bf   = U;
    __bf16* xT      = U + (size_t)NELEM;
    __bf16* Wout_bf = U + 2 * (size_t)NELEM;
    float*  y       = (float*)(U + 3 * (size_t)NELEM);
    __bf16* vtb     = U + 5 * (size_t)NELEM;
    float*  qp      = (float*)U;
    __bf16* qrot    = U + 3 * (size_t)NELEM;
    __bf16* attnT   = U + 4 * (size_t)NELEM;

    // 0. weight casts + x transpose-cast
    cast_bf16<<<NELEM / (8 * 256), 256, 0, stream>>>(Wq_lin, Wq_bf);
    cast_bf16<<<NELEM / (8 * 256), 256, 0, stream>>>(Wout, Wout_bf);
    transpose_cast_x<<<dim3(Ww / 64, BINS / 64, Bb * Cc_), 256, 0, stream>>>(x, xT);
    // 1. y = Wq_lin @ x   (MFMA)
    gemm_bt<<<dim3(Ww / 128, BINS / 128, Bb * Cc_), 256, 0, stream>>>(Wq_bf, xT, y);
    // 2. qp = conv1x3(y) + bias; bf16 copy = V^T
    conv1x3<<<dim3(BINS, Bb), 256, 0, stream>>>(y, Wq_conv, bq_conv, qp, vtb);
    // 3. rotary + transpose -> qrot bf16
    rotary_transpose<<<dim3(Ww / 64, Bb * Cc_ * HEADS), 256, 0, stream>>>(qp, qrot);
    // 4. MFMA flash attention -> attnT bf16 [bc][p][bins]
    attn_mfma<<<dim3(Ww / 64, Bb * Cc_ * HEADS), 256, 0, stream>>>(qrot, vtb, attnT);
    // 5. out = Wout @ attn  (MFMA)
    gemm_bt<<<dim3(Ww / 128, BINS / 128, Bb * Cc_), 256, 0, stream>>>(Wout_bf, attnT, out);
}

// Round 4
// 275.664 us; speedup vs baseline: 4.9616x; 1.1921x over previous
//
#include <hip/hip_runtime.h>
#include <cstddef>

// Problem constants
#define Bb 2
#define Cc_ 8
#define BINS 1024
#define Ww 512
#define HEADS 8
#define HD 128
#define NELEM (Bb*Cc_*BINS*Ww)   // 8388608

typedef __attribute__((ext_vector_type(8)))  __bf16 bf16x8;
typedef __attribute__((ext_vector_type(4)))  __bf16 bf16x4;
typedef __attribute__((ext_vector_type(4)))  float  f32x4;
typedef __attribute__((ext_vector_type(16))) float  f32x16;
#define MFMA32(a,b,c) __builtin_amdgcn_mfma_f32_32x32x16_bf16(a,b,c,0,0,0)

// async global->LDS: lane i's 16B lands at ldsbase + i*16; global addr is a
// per-lane gather, so we pre-swizzle by computing the SOURCE of each slot.
__device__ __forceinline__ void async16(const __bf16* g, __bf16* l) {
    __builtin_amdgcn_global_load_lds(
        (const __attribute__((address_space(1))) void*)g,
        (__attribute__((address_space(3))) void*)l, 16, 0, 0);
}

// ---------------------------------------------------------------------------
// f32 -> bf16 cast (weights)
// ---------------------------------------------------------------------------
__global__ void __launch_bounds__(256) cast_bf16(const float* __restrict__ in,
                                                 __bf16* __restrict__ out) {
    size_t i = ((size_t)blockIdx.x * 256 + threadIdx.x) * 8;
    float4 a = *(const float4*)&in[i];
    float4 b = *(const float4*)&in[i + 4];
    bf16x8 o = {(__bf16)a.x, (__bf16)a.y, (__bf16)a.z, (__bf16)a.w,
                (__bf16)b.x, (__bf16)b.y, (__bf16)b.z, (__bf16)b.w};
    *(bf16x8*)&out[i] = o;
}

// ---------------------------------------------------------------------------
// x [bc][i][w] f32 -> xT [bc][w][i] bf16 (B^T layout for gemm)
// ---------------------------------------------------------------------------
__global__ void __launch_bounds__(256) transpose_cast_x(const float* __restrict__ x,
                                                        __bf16* __restrict__ xT) {
    int w0 = blockIdx.x * 64, i0 = blockIdx.y * 64, bc = blockIdx.z;
    const float* src = x + (size_t)bc * BINS * Ww;
    __bf16* dst = xT + (size_t)bc * Ww * BINS;
    __shared__ float T[64][65];
    int t = threadIdx.x;
    #pragma unroll
    for (int pass = 0; pass < 4; pass++) {
        int idx = t + pass * 256;
        int il = idx >> 4, ch = idx & 15;
        float4 v = *(const float4*)&src[(size_t)(i0 + il) * Ww + w0 + ch * 4];
        T[il][ch * 4 + 0] = v.x; T[il][ch * 4 + 1] = v.y;
        T[il][ch * 4 + 2] = v.z; T[il][ch * 4 + 3] = v.w;
    }
    __syncthreads();
    #pragma unroll
    for (int pass = 0; pass < 2; pass++) {
        int idx = t + pass * 256;
        int wl = idx >> 3, ch = idx & 7;
        bf16x8 o;
        #pragma unroll
        for (int j = 0; j < 8; j++) o[j] = (__bf16)T[ch * 8 + j][wl];
        *(bf16x8*)&dst[(size_t)(w0 + wl) * BINS + i0 + ch * 8] = o;
    }
}

// ---------------------------------------------------------------------------
// bf16 GEMM, 32x32x16 MFMA. Y[bc][m][n] = sum_k A[c][m][k]*Bt[bc][n][k]
// 128x128 tile, BK=32, 4 waves each 64x64 (2x2 of 32x32).
// LDS rows 32 bf16 (64B, 4 16B-chunks), XOR swizzle chunk^=(row&3) via
// gathered async16 -> bank-uniform frag reads, no padding.
// ---------------------------------------------------------------------------
template<bool BF16OUT>
__global__ void __launch_bounds__(256) gemm32(const __bf16* __restrict__ Wall,
                                              const __bf16* __restrict__ Bt,
                                              void* __restrict__ Yv) {
    int bc = blockIdx.z, c = bc & 7;
    const __bf16* A  = Wall + (size_t)c  * BINS * BINS;   // [m][k]
    const __bf16* Bm = Bt   + (size_t)bc * Ww * BINS;     // [n][k]
    int n0 = blockIdx.x * 128, m0 = blockIdx.y * 128;

    __shared__ __bf16 Asm[128 * 32];
    __shared__ __bf16 Bsm[128 * 32];

    int t = threadIdx.x, w = t >> 6, l = t & 63;
    int l31 = l & 31, h = l >> 5;
    int wm = w >> 1, wn = w & 1;

    // staging decode: LDS slot p -> (row, swizzled source chunk)
    int rowS[2], colS[2];
    #pragma unroll
    for (int j = 0; j < 2; j++) {
        int p = (w * 2 + j) * 64 + l;
        int r = p >> 2, cs = (p & 3) ^ (r & 3);
        rowS[j] = r; colS[j] = cs * 8;
    }

    f32x16 acc[2][2];
    #pragma unroll
    for (int a = 0; a < 2; a++)
        #pragma unroll
        for (int b = 0; b < 2; b++)
            #pragma unroll
            for (int r = 0; r < 16; r++) acc[a][b][r] = 0.f;

    for (int k0 = 0; k0 < BINS; k0 += 32) {
        __syncthreads();
        #pragma unroll
        for (int j = 0; j < 2; j++) {
            async16(A  + (size_t)(m0 + rowS[j]) * BINS + k0 + colS[j],
                    Asm + (w * 2 + j) * 512);
            async16(Bm + (size_t)(n0 + rowS[j]) * BINS + k0 + colS[j],
                    Bsm + (w * 2 + j) * 512);
        }
        __syncthreads();
        bf16x8 af[2][2], bfr[2][2];
        #pragma unroll
        for (int mt = 0; mt < 2; mt++)
            #pragma unroll
            for (int kc = 0; kc < 2; kc++) {
                int row = wm * 64 + mt * 32 + l31;
                int ch = (kc * 2 + h) ^ (row & 3);
                af[mt][kc] = *(bf16x8*)&Asm[row * 32 + ch * 8];
            }
        #pragma unroll
        for (int nt = 0; nt < 2; nt++)
            #pragma unroll
            for (int kc = 0; kc < 2; kc++) {
                int row = wn * 64 + nt * 32 + l31;
                int ch = (kc * 2 + h) ^ (row & 3);
                bfr[nt][kc] = *(bf16x8*)&Bsm[row * 32 + ch * 8];
            }
        #pragma unroll
        for (int kc = 0; kc < 2; kc++)
            #pragma unroll
            for (int mt = 0; mt < 2; mt++)
                #pragma unroll
                for (int nt = 0; nt < 2; nt++)
                    acc[mt][nt] = MFMA32(af[mt][kc], bfr[nt][kc], acc[mt][nt]);
    }

    // C/D: col = lane&31, row = (reg&3) + 8*(reg>>2) + 4*(lane>>5)
    #pragma unroll
    for (int mt = 0; mt < 2; mt++)
        #pragma unroll
        for (int nt = 0; nt < 2; nt++)
            #pragma unroll
            for (int reg = 0; reg < 16; reg++) {
                int m = m0 + wm * 64 + mt * 32 + (reg & 3) + 8 * (reg >> 2) + 4 * h;
                int n = n0 + wn * 64 + nt * 32 + l31;
                if constexpr (BF16OUT) {
                    __bf16* Cm = (__bf16*)Yv + (size_t)bc * BINS * Ww;
                    Cm[(size_t)m * Ww + n] = (__bf16)acc[mt][nt][reg];
                } else {
                    float* Cm = (float*)Yv + (size_t)bc * BINS * Ww;
                    Cm[(size_t)m * Ww + n] = acc[mt][nt][reg];
                }
            }
}

// ---------------------------------------------------------------------------
// cross-channel 1x3 conv + bias, bf16 in (y), bf16 out (vt = qp, V^T layout)
// ---------------------------------------------------------------------------
__global__ void __launch_bounds__(256) conv1x3(const __bf16* __restrict__ y,
                                               const float* __restrict__ Wc,
                                               const float* __restrict__ bias,
                                               __bf16* __restrict__ vt) {
    int h = blockIdx.x, b = blockIdx.y;
    __shared__ float ys[8][514];
    __shared__ float wgt[192];
    __shared__ float bs[8];
    int t = threadIdx.x;
    if (t < 192) wgt[t] = Wc[t];
    if (t < 8) { bs[t] = bias[t]; ys[t][0] = 0.f; ys[t][513] = 0.f; }
    for (int i = t; i < 512; i += 256) {
        int ci = i >> 6, ch = i & 63;
        bf16x8 v = *(const bf16x8*)&y[((size_t)(b * 8 + ci) * BINS + h) * Ww + ch * 8];
        #pragma unroll
        for (int j = 0; j < 8; j++) ys[ci][ch * 8 + j + 1] = (float)v[j];
    }
    __syncthreads();
    for (int w = t; w < 512; w += 256) {
        #pragma unroll
        for (int co = 0; co < 8; co++) {
            float s = bs[co];
            #pragma unroll
            for (int ci = 0; ci < 8; ci++) {
                const float* wp = &wgt[(co * 8 + ci) * 3];
                s += ys[ci][w + 0] * wp[0] + ys[ci][w + 1] * wp[1] + ys[ci][w + 2] * wp[2];
            }
            vt[((size_t)(b * 8 + co) * BINS + h) * Ww + w] = (__bf16)s;
        }
    }
}

// ---------------------------------------------------------------------------
// rotary + transpose: vt bf16 [bch][d][p] -> qrot bf16 [bch][p][d]
// ---------------------------------------------------------------------------
__global__ void __launch_bounds__(256) rotary_transpose(const __bf16* __restrict__ vt,
                                                        __bf16* __restrict__ qrot) {
    int p0  = blockIdx.x * 64;
    int bch = blockIdx.y;
    int t = threadIdx.x;
    __shared__ float T[64 * 129];   // [p_local][d]

    const __bf16* src = vt + (size_t)bch * HD * Ww;
    for (int pass = 0; pass < 4; pass++) {
        int idx = t + pass * 256;          // 0..1023
        int d = idx >> 3, ch = idx & 7;    // 8 x bf16x8 per d-row
        bf16x8 v = *(const bf16x8*)&src[(size_t)d * Ww + p0 + ch * 8];
        #pragma unroll
        for (int j = 0; j < 8; j++) T[(ch * 8 + j) * 129 + d] = (float)v[j];
    }
    __syncthreads();
    for (int pass = 0; pass < 4; pass++) {
        int idx = t + pass * 256;
        int p = idx >> 4, chunk = idx & 15;
        float pos = (float)(p0 + p);
        bf16x8 o;
        if (chunk < 8) {
            #pragma unroll
            for (int j = 0; j < 8; j += 2) {
                int d = chunk * 8 + j;
                int jj = d >> 1;
                float inv = __expf(-(2.0f * jj / 64.0f) * 9.210340371976184f);
                float sn, cs;
                __sincosf(pos * inv, &sn, &cs);
                float x1 = T[p * 129 + d];
                float x2 = T[p * 129 + d + 1];
                o[j]     = (__bf16)(x1 * cs - x2 * sn);
                o[j + 1] = (__bf16)(x2 * cs + x1 * sn);
            }
        } else {
            #pragma unroll
            for (int j = 0; j < 8; j++)
                o[j] = (__bf16)T[p * 129 + chunk * 8 + j];
        }
        *(bf16x8*)&qrot[((size_t)bch * Ww + p0 + p) * HD + chunk * 8] = o;
    }
}

// ---------------------------------------------------------------------------
// Flash attention, 32x32x16 MFMA, S^T orientation.
// Block = q-tile 128 x one bch; wave owns 32 q-rows (Q as B-frags in regs).
// S^T = K·Q^T  -> lane col = its q-row -> softmax is in-register + 1 shuffle.
// O^T = V^T·P  (P wave-private in LDS: no barrier between QK and PV).
// XOR-swizzled LDS via gathered async16; 2 barriers per K-tile.
// ---------------------------------------------------------------------------
__global__ void __launch_bounds__(256, 2) attn32(const __bf16* __restrict__ qrot,
                                                 const __bf16* __restrict__ vt,
                                                 __bf16* __restrict__ attnT) {
    int bid = blockIdx.x;
    int bch = bid & 127, q0 = (bid >> 7) * 128;   // same-bch blocks: id stride 128 = same XCD
    int t = threadIdx.x, wv = t >> 6, lane = t & 63;
    int l31 = lane & 31, h = lane >> 5;

    __shared__ __align__(16) char smem[49152];
    __bf16* Ks  = (__bf16*)smem;                        // 64 kpos x 128 d   (chunk ^= r&15)
    __bf16* Vts = (__bf16*)(smem + 16384);              // 128 d  x 64 kpos  (chunk ^= r&7)
    __bf16* Psw = (__bf16*)(smem + 32768) + wv * 2048;  // 32 qr x 64 kpos, per wave (chunk ^= qr&7)

    const __bf16* qb = qrot + (size_t)bch * Ww * HD;   // [p][d]
    const __bf16* vb = vt   + (size_t)bch * HD * Ww;   // [d][p]

    // Q B-frags (row n = qrow = lane&31, k-chunk = c*16 + h*8), scale folded in
    int qrow = q0 + wv * 32 + l31;
    bf16x8 qf[8];
    #pragma unroll
    for (int c = 0; c < 8; c++) {
        bf16x8 v = *(const bf16x8*)&qb[(size_t)qrow * HD + c * 16 + h * 8];
        #pragma unroll
        for (int j = 0; j < 8; j++) v[j] = (__bf16)((float)v[j] * 0.03125f);
        qf[c] = v;
    }

    f32x16 oacc[4];
    #pragma unroll
    for (int dt = 0; dt < 4; dt++)
        #pragma unroll
        for (int r = 0; r < 16; r++) oacc[dt][r] = 0.f;
    float m_st = -1e30f, l_st = 0.f;

    for (int kt = 0; kt < 8; kt++) {
        int k0 = kt * 64;
        __syncthreads();
        #pragma unroll
        for (int i = 0; i < 4; i++) {
            int p = wv * 256 + i * 64 + lane;
            int r  = p >> 4, cs  = ((p & 15) ^ (r & 15)) * 8;
            async16(qb + (size_t)(k0 + r) * HD + cs, Ks + (wv * 256 + i * 64) * 8);
            int r2 = p >> 3, cs2 = ((p & 7) ^ (r2 & 7)) * 8;
            async16(vb + (size_t)r2 * Ww + k0 + cs2, Vts + (wv * 256 + i * 64) * 8);
        }
        __syncthreads();

        // S^T = K·Q^T : C col = qrow, row = kpos (regmap)
        f32x16 st[2];
        #pragma unroll
        for (int t2 = 0; t2 < 2; t2++)
            #pragma unroll
            for (int r = 0; r < 16; r++) st[t2][r] = 0.f;
        #pragma unroll
        for (int c = 0; c < 8; c++)
            #pragma unroll
            for (int t2 = 0; t2 < 2; t2++) {
                int row = t2 * 32 + l31;
                int ch = (c * 2 + h) ^ (row & 15);
                bf16x8 ak = *(bf16x8*)&Ks[row * 128 + ch * 8];
                st[t2] = MFMA32(ak, qf[c], st[t2]);
            }

        // online softmax: all 32 values in-lane share one q-row
        float mx = -1e30f;
        #pragma unroll
        for (int t2 = 0; t2 < 2; t2++)
            #pragma unroll
            for (int r = 0; r < 16; r++) mx = fmaxf(mx, st[t2][r]);
        mx = fmaxf(mx, __shfl_xor(mx, 32));
        float mnew = fmaxf(m_st, mx);
        float alpha = __expf(m_st - mnew);
        float sum = 0.f;
        #pragma unroll
        for (int t2 = 0; t2 < 2; t2++)
            #pragma unroll
            for (int r = 0; r < 16; r++) {
                float p = __expf(st[t2][r] - mnew);
                st[t2][r] = p;
                sum += p;
            }
        sum += __shfl_xor(sum, 32);
        l_st = l_st * alpha + sum;
        m_st = mnew;

        // P -> wave-private LDS (packed b64; kpos of regs 4g..4g+3 contiguous)
        #pragma unroll
        for (int t2 = 0; t2 < 2; t2++)
            #pragma unroll
            for (int g = 0; g < 4; g++) {
                bf16x4 pk = {(__bf16)st[t2][4 * g],     (__bf16)st[t2][4 * g + 1],
                             (__bf16)st[t2][4 * g + 2], (__bf16)st[t2][4 * g + 3]};
                int ch = (t2 * 4 + g) ^ (l31 & 7);
                *(bf16x4*)&Psw[l31 * 64 + ch * 8 + 4 * h] = pk;
            }
        #pragma unroll
        for (int dt = 0; dt < 4; dt++)
            #pragma unroll
            for (int r = 0; r < 16; r++) oacc[dt][r] *= alpha;

        // O^T += V^T·P : A = V^T rows (d), B = P rows (qrow)
        #pragma unroll
        for (int kc = 0; kc < 4; kc++) {
            int chp = (kc * 2 + h) ^ (l31 & 7);
            bf16x8 bp = *(bf16x8*)&Psw[l31 * 64 + chp * 8];
            #pragma unroll
            for (int dt = 0; dt < 4; dt++) {
                int row = dt * 32 + l31;
                int cv = (kc * 2 + h) ^ (row & 7);
                bf16x8 av = *(bf16x8*)&Vts[row * 64 + cv * 8];
                oacc[dt] = MFMA32(av, bp, oacc[dt]);
            }
        }
    }

    // epilogue: O^T (col = qrow, row = d) -> wave LDS [qrow][d] -> coalesced
    // bf16x8 stores to attnT[bc][p][bins] (B^T layout for final gemm)
    __syncthreads();
    __bf16* Ob = (__bf16*)smem + wv * 4096;   // 32 x 128 (chunk ^= qr&15)
    float linv = 1.f / l_st;
    #pragma unroll
    for (int dt = 0; dt < 4; dt++)
        #pragma unroll
        for (int g = 0; g < 4; g++) {
            bf16x4 pk = {(__bf16)(oacc[dt][4 * g] * linv),
                         (__bf16)(oacc[dt][4 * g + 1] * linv),
                         (__bf16)(oacc[dt][4 * g + 2] * linv),
                         (__bf16)(oacc[dt][4 * g + 3] * linv)};
            int ch = (dt * 4 + g) ^ (l31 & 15);
            *(bf16x4*)&Ob[l31 * 128 + ch * 8 + 4 * h] = pk;
        }
    int bc = bch >> 3, h0 = bch & 7;
    #pragma unroll
    for (int i = 0; i < 8; i++) {
        int p = i * 64 + lane;
        int rr = p >> 4, cc = p & 15;
        int cs = cc ^ (rr & 15);
        bf16x8 v = *(bf16x8*)&Ob[rr * 128 + cs * 8];
        *(bf16x8*)&attnT[((size_t)bc * Ww + q0 + wv * 32 + rr) * BINS + h0 * HD + cc * 8] = v;
    }
}

// ---------------------------------------------------------------------------
// Launch. Workspace: 6 slots of NELEM bf16 = 100.66 MB.
//  U0 Wq_bf | U1 xT | U2 Wout_bf | U3 y(bf16) -> attnT | U4 vt | U5 qrot
// ---------------------------------------------------------------------------
extern "C" void kernel_launch(void* const* d_in, const int* in_sizes, int n_in,
                              void* d_out, int out_size, void* d_ws, size_t ws_size,
                              hipStream_t stream) {
    const float* x       = (const float*)d_in[0];
    const float* Wq_lin  = (const float*)d_in[1];
    const float* Wq_conv = (const float*)d_in[2];
    const float* bq_conv = (const float*)d_in[3];
    const float* Wout    = (const float*)d_in[4];
    float* out = (float*)d_out;

    __bf16* U = (__bf16*)d_ws;
    __bf16* Wq_bf   = U;
    __bf16* xT      = U + 1 * (size_t)NELEM;
    __bf16* Wout_bf = U + 2 * (size_t)NELEM;
    __bf16* y       = U + 3 * (size_t)NELEM;
    __bf16* vtb     = U + 4 * (size_t)NELEM;
    __bf16* qrot    = U + 5 * (size_t)NELEM;
    __bf16* attnT   = U + 3 * (size_t)NELEM;   // y dead after conv

    cast_bf16<<<NELEM / (8 * 256), 256, 0, stream>>>(Wq_lin, Wq_bf);
    cast_bf16<<<NELEM / (8 * 256), 256, 0, stream>>>(Wout, Wout_bf);
    transpose_cast_x<<<dim3(Ww / 64, BINS / 64, Bb * Cc_), 256, 0, stream>>>(x, xT);
    // 1. y = Wq_lin @ x  (bf16 out)
    gemm32<true><<<dim3(Ww / 128, BINS / 128, Bb * Cc_), 256, 0, stream>>>(Wq_bf, xT, y);
    // 2. vt = bf16(conv1x3(y) + bias)   (= V^T layout)
    conv1x3<<<dim3(BINS, Bb), 256, 0, stream>>>(y, Wq_conv, bq_conv, vtb);
    // 3. qrot = rotary(vt), transposed to [bch][p][d]
    rotary_transpose<<<dim3(Ww / 64, Bb * Cc_ * HEADS), 256, 0, stream>>>(vtb, qrot);
    // 4. attention -> attnT bf16 [bc][p][bins]
    attn32<<<dim3((Ww / 128) * 128), 256, 0, stream>>>(qrot, vtb, attnT);
    // 5. out = Wout @ attn  (f32 out)
    gemm32<false><<<dim3(Ww / 128, BINS / 128, Bb * Cc_), 256, 0, stream>>>(Wout_bf, attnT, out);
}

// Round 5
// 253.031 us; speedup vs baseline: 5.4054x; 1.0895x over previous
//
#include <hip/hip_runtime.h>
#include <cstddef>

// Problem constants
#define Bb 2
#define Cc_ 8
#define BINS 1024
#define Ww 512
#define HEADS 8
#define HD 128
#define NELEM (Bb*Cc_*BINS*Ww)   // 8388608

typedef __attribute__((ext_vector_type(8)))  __bf16 bf16x8;
typedef __attribute__((ext_vector_type(4)))  __bf16 bf16x4;
typedef __attribute__((ext_vector_type(4)))  float  f32x4;
typedef __attribute__((ext_vector_type(16))) float  f32x16;
#define MFMA32(a,b,c) __builtin_amdgcn_mfma_f32_32x32x16_bf16(a,b,c,0,0,0)

// async global->LDS: lane i's 16B lands at ldsbase + i*16; global addr is a
// per-lane gather, so we pre-swizzle by computing the SOURCE of each slot.
__device__ __forceinline__ void async16(const __bf16* g, __bf16* l) {
    __builtin_amdgcn_global_load_lds(
        (const __attribute__((address_space(1))) void*)g,
        (__attribute__((address_space(3))) void*)l, 16, 0, 0);
}

// ---------------------------------------------------------------------------
// f32 -> bf16 cast for BOTH weight matrices in one launch (blockIdx.y picks).
// ---------------------------------------------------------------------------
__global__ void __launch_bounds__(256) cast_bf16_2(const float* __restrict__ inA,
                                                   const float* __restrict__ inB,
                                                   __bf16* __restrict__ outA,
                                                   __bf16* __restrict__ outB) {
    const float* in = blockIdx.y ? inB : inA;
    __bf16* out     = blockIdx.y ? outB : outA;
    size_t i = ((size_t)blockIdx.x * 256 + threadIdx.x) * 8;
    float4 a = *(const float4*)&in[i];
    float4 b = *(const float4*)&in[i + 4];
    bf16x8 o = {(__bf16)a.x, (__bf16)a.y, (__bf16)a.z, (__bf16)a.w,
                (__bf16)b.x, (__bf16)b.y, (__bf16)b.z, (__bf16)b.w};
    *(bf16x8*)&out[i] = o;
}

// ---------------------------------------------------------------------------
// x [bc][i][w] f32 -> xT [bc][w][i] bf16 (B^T layout for gemm)
// ---------------------------------------------------------------------------
__global__ void __launch_bounds__(256) transpose_cast_x(const float* __restrict__ x,
                                                        __bf16* __restrict__ xT) {
    int w0 = blockIdx.x * 64, i0 = blockIdx.y * 64, bc = blockIdx.z;
    const float* src = x + (size_t)bc * BINS * Ww;
    __bf16* dst = xT + (size_t)bc * Ww * BINS;
    __shared__ float T[64][65];
    int t = threadIdx.x;
    #pragma unroll
    for (int pass = 0; pass < 4; pass++) {
        int idx = t + pass * 256;
        int il = idx >> 4, ch = idx & 15;
        float4 v = *(const float4*)&src[(size_t)(i0 + il) * Ww + w0 + ch * 4];
        T[il][ch * 4 + 0] = v.x; T[il][ch * 4 + 1] = v.y;
        T[il][ch * 4 + 2] = v.z; T[il][ch * 4 + 3] = v.w;
    }
    __syncthreads();
    #pragma unroll
    for (int pass = 0; pass < 2; pass++) {
        int idx = t + pass * 256;
        int wl = idx >> 3, ch = idx & 7;
        bf16x8 o;
        #pragma unroll
        for (int j = 0; j < 8; j++) o[j] = (__bf16)T[ch * 8 + j][wl];
        *(bf16x8*)&dst[(size_t)(w0 + wl) * BINS + i0 + ch * 8] = o;
    }
}

// ---------------------------------------------------------------------------
// bf16 GEMM, 32x32x16 MFMA. Y[bc][m][n] = sum_k A[c][m][k]*Bt[bc][n][k]
// 128x128 tile, BK=32, 4 waves each 64x64 (2x2 of 32x32).
// XOR-swizzled LDS via gathered async16, no padding.
// ---------------------------------------------------------------------------
template<bool BF16OUT>
__global__ void __launch_bounds__(256) gemm32(const __bf16* __restrict__ Wall,
                                              const __bf16* __restrict__ Bt,
                                              void* __restrict__ Yv) {
    int bc = blockIdx.z, c = bc & 7;
    const __bf16* A  = Wall + (size_t)c  * BINS * BINS;   // [m][k]
    const __bf16* Bm = Bt   + (size_t)bc * Ww * BINS;     // [n][k]
    int n0 = blockIdx.x * 128, m0 = blockIdx.y * 128;

    __shared__ __bf16 Asm[128 * 32];
    __shared__ __bf16 Bsm[128 * 32];

    int t = threadIdx.x, w = t >> 6, l = t & 63;
    int l31 = l & 31, h = l >> 5;
    int wm = w >> 1, wn = w & 1;

    int rowS[2], colS[2];
    #pragma unroll
    for (int j = 0; j < 2; j++) {
        int p = (w * 2 + j) * 64 + l;
        int r = p >> 2, cs = (p & 3) ^ (r & 3);
        rowS[j] = r; colS[j] = cs * 8;
    }

    f32x16 acc[2][2];
    #pragma unroll
    for (int a = 0; a < 2; a++)
        #pragma unroll
        for (int b = 0; b < 2; b++)
            #pragma unroll
            for (int r = 0; r < 16; r++) acc[a][b][r] = 0.f;

    for (int k0 = 0; k0 < BINS; k0 += 32) {
        __syncthreads();
        #pragma unroll
        for (int j = 0; j < 2; j++) {
            async16(A  + (size_t)(m0 + rowS[j]) * BINS + k0 + colS[j],
                    Asm + (w * 2 + j) * 512);
            async16(Bm + (size_t)(n0 + rowS[j]) * BINS + k0 + colS[j],
                    Bsm + (w * 2 + j) * 512);
        }
        __syncthreads();
        bf16x8 af[2][2], bfr[2][2];
        #pragma unroll
        for (int mt = 0; mt < 2; mt++)
            #pragma unroll
            for (int kc = 0; kc < 2; kc++) {
                int row = wm * 64 + mt * 32 + l31;
                int ch = (kc * 2 + h) ^ (row & 3);
                af[mt][kc] = *(bf16x8*)&Asm[row * 32 + ch * 8];
            }
        #pragma unroll
        for (int nt = 0; nt < 2; nt++)
            #pragma unroll
            for (int kc = 0; kc < 2; kc++) {
                int row = wn * 64 + nt * 32 + l31;
                int ch = (kc * 2 + h) ^ (row & 3);
                bfr[nt][kc] = *(bf16x8*)&Bsm[row * 32 + ch * 8];
            }
        #pragma unroll
        for (int kc = 0; kc < 2; kc++)
            #pragma unroll
            for (int mt = 0; mt < 2; mt++)
                #pragma unroll
                for (int nt = 0; nt < 2; nt++)
                    acc[mt][nt] = MFMA32(af[mt][kc], bfr[nt][kc], acc[mt][nt]);
    }

    // C/D: col = lane&31, row = (reg&3) + 8*(reg>>2) + 4*(lane>>5)
    #pragma unroll
    for (int mt = 0; mt < 2; mt++)
        #pragma unroll
        for (int nt = 0; nt < 2; nt++)
            #pragma unroll
            for (int reg = 0; reg < 16; reg++) {
                int m = m0 + wm * 64 + mt * 32 + (reg & 3) + 8 * (reg >> 2) + 4 * h;
                int n = n0 + wn * 64 + nt * 32 + l31;
                if constexpr (BF16OUT) {
                    __bf16* Cm = (__bf16*)Yv + (size_t)bc * BINS * Ww;
                    Cm[(size_t)m * Ww + n] = (__bf16)acc[mt][nt][reg];
                } else {
                    float* Cm = (float*)Yv + (size_t)bc * BINS * Ww;
                    Cm[(size_t)m * Ww + n] = acc[mt][nt][reg];
                }
            }
}

// ---------------------------------------------------------------------------
// cross-channel 1x3 conv + bias — register form, no LDS.
// Thread owns an 8-wide w-chunk of one (b,h) row for ALL 8 output channels.
// y neighborhood (8 ci x 10 vals) in VGPRs; weights/bias are block-uniform
// global reads -> SGPR (scalar operand in the FMA).
// ---------------------------------------------------------------------------
__global__ void __launch_bounds__(256) conv1x3_reg(const __bf16* __restrict__ y,
                                                   const float* __restrict__ Wc,
                                                   const float* __restrict__ bias,
                                                   __bf16* __restrict__ vt) {
    int tid = blockIdx.x * 256 + threadIdx.x;      // 131072 total
    int wc = tid & 63;                             // w-chunk (lane-varying)
    int h  = (tid >> 6) & 1023;
    int b  = tid >> 16;
    int w0 = wc * 8;

    float ym[8][8], yl[8], yr[8];
    #pragma unroll
    for (int ci = 0; ci < 8; ci++) {
        const __bf16* row = y + ((size_t)(b * 8 + ci) * BINS + h) * Ww;
        bf16x8 v = *(const bf16x8*)&row[w0];
        #pragma unroll
        for (int j = 0; j < 8; j++) ym[ci][j] = (float)v[j];
        yl[ci] = (w0 > 0)   ? (float)row[w0 - 1] : 0.f;
        yr[ci] = (w0 < 504) ? (float)row[w0 + 8] : 0.f;
    }
    #pragma unroll
    for (int co = 0; co < 8; co++) {
        float acc[8];
        float bv = bias[co];
        #pragma unroll
        for (int j = 0; j < 8; j++) acc[j] = bv;
        #pragma unroll
        for (int ci = 0; ci < 8; ci++) {
            float wa = Wc[(co * 8 + ci) * 3 + 0];
            float wb = Wc[(co * 8 + ci) * 3 + 1];
            float wcc = Wc[(co * 8 + ci) * 3 + 2];
            acc[0] += yl[ci] * wa;
            #pragma unroll
            for (int j = 1; j < 8; j++) acc[j] += ym[ci][j - 1] * wa;
            #pragma unroll
            for (int j = 0; j < 8; j++) acc[j] += ym[ci][j] * wb;
            #pragma unroll
            for (int j = 0; j < 7; j++) acc[j] += ym[ci][j + 1] * wcc;
            acc[7] += yr[ci] * wcc;
        }
        bf16x8 o;
        #pragma unroll
        for (int j = 0; j < 8; j++) o[j] = (__bf16)acc[j];
        *(bf16x8*)&vt[((size_t)(b * 8 + co) * BINS + h) * Ww + w0] = o;
    }
}

// ---------------------------------------------------------------------------
// rotary + transpose: vt bf16 [bch][d][p] -> qrot bf16 [bch][p][d]
// ---------------------------------------------------------------------------
__global__ void __launch_bounds__(256) rotary_transpose(const __bf16* __restrict__ vt,
                                                        __bf16* __restrict__ qrot) {
    int p0  = blockIdx.x * 64;
    int bch = blockIdx.y;
    int t = threadIdx.x;
    __shared__ float T[64 * 129];   // [p_local][d]

    const __bf16* src = vt + (size_t)bch * HD * Ww;
    for (int pass = 0; pass < 4; pass++) {
        int idx = t + pass * 256;
        int d = idx >> 3, ch = idx & 7;
        bf16x8 v = *(const bf16x8*)&src[(size_t)d * Ww + p0 + ch * 8];
        #pragma unroll
        for (int j = 0; j < 8; j++) T[(ch * 8 + j) * 129 + d] = (float)v[j];
    }
    __syncthreads();
    for (int pass = 0; pass < 4; pass++) {
        int idx = t + pass * 256;
        int p = idx >> 4, chunk = idx & 15;
        float pos = (float)(p0 + p);
        bf16x8 o;
        if (chunk < 8) {
            #pragma unroll
            for (int j = 0; j < 8; j += 2) {
                int d = chunk * 8 + j;
                int jj = d >> 1;
                float inv = __expf(-(2.0f * jj / 64.0f) * 9.210340371976184f);
                float sn, cs;
                __sincosf(pos * inv, &sn, &cs);
                float x1 = T[p * 129 + d];
                float x2 = T[p * 129 + d + 1];
                o[j]     = (__bf16)(x1 * cs - x2 * sn);
                o[j + 1] = (__bf16)(x2 * cs + x1 * sn);
            }
        } else {
            #pragma unroll
            for (int j = 0; j < 8; j++)
                o[j] = (__bf16)T[p * 129 + chunk * 8 + j];
        }
        *(bf16x8*)&qrot[((size_t)bch * Ww + p0 + p) * HD + chunk * 8] = o;
    }
}

// ---------------------------------------------------------------------------
// Flash attention, 32x32x16 MFMA, S^T orientation (unchanged from R4).
// ---------------------------------------------------------------------------
__global__ void __launch_bounds__(256, 2) attn32(const __bf16* __restrict__ qrot,
                                                 const __bf16* __restrict__ vt,
                                                 __bf16* __restrict__ attnT) {
    int bid = blockIdx.x;
    int bch = bid & 127, q0 = (bid >> 7) * 128;
    int t = threadIdx.x, wv = t >> 6, lane = t & 63;
    int l31 = lane & 31, h = lane >> 5;

    __shared__ __align__(16) char smem[49152];
    __bf16* Ks  = (__bf16*)smem;                        // 64 kpos x 128 d   (chunk ^= r&15)
    __bf16* Vts = (__bf16*)(smem + 16384);              // 128 d  x 64 kpos  (chunk ^= r&7)
    __bf16* Psw = (__bf16*)(smem + 32768) + wv * 2048;  // 32 qr x 64 kpos, per wave

    const __bf16* qb = qrot + (size_t)bch * Ww * HD;   // [p][d]
    const __bf16* vb = vt   + (size_t)bch * HD * Ww;   // [d][p]

    int qrow = q0 + wv * 32 + l31;
    bf16x8 qf[8];
    #pragma unroll
    for (int c = 0; c < 8; c++) {
        bf16x8 v = *(const bf16x8*)&qb[(size_t)qrow * HD + c * 16 + h * 8];
        #pragma unroll
        for (int j = 0; j < 8; j++) v[j] = (__bf16)((float)v[j] * 0.03125f);
        qf[c] = v;
    }

    f32x16 oacc[4];
    #pragma unroll
    for (int dt = 0; dt < 4; dt++)
        #pragma unroll
        for (int r = 0; r < 16; r++) oacc[dt][r] = 0.f;
    float m_st = -1e30f, l_st = 0.f;

    for (int kt = 0; kt < 8; kt++) {
        int k0 = kt * 64;
        __syncthreads();
        #pragma unroll
        for (int i = 0; i < 4; i++) {
            int p = wv * 256 + i * 64 + lane;
            int r  = p >> 4, cs  = ((p & 15) ^ (r & 15)) * 8;
            async16(qb + (size_t)(k0 + r) * HD + cs, Ks + (wv * 256 + i * 64) * 8);
            int r2 = p >> 3, cs2 = ((p & 7) ^ (r2 & 7)) * 8;
            async16(vb + (size_t)r2 * Ww + k0 + cs2, Vts + (wv * 256 + i * 64) * 8);
        }
        __syncthreads();

        f32x16 st[2];
        #pragma unroll
        for (int t2 = 0; t2 < 2; t2++)
            #pragma unroll
            for (int r = 0; r < 16; r++) st[t2][r] = 0.f;
        #pragma unroll
        for (int c = 0; c < 8; c++)
            #pragma unroll
            for (int t2 = 0; t2 < 2; t2++) {
                int row = t2 * 32 + l31;
                int ch = (c * 2 + h) ^ (row & 15);
                bf16x8 ak = *(bf16x8*)&Ks[row * 128 + ch * 8];
                st[t2] = MFMA32(ak, qf[c], st[t2]);
            }

        float mx = -1e30f;
        #pragma unroll
        for (int t2 = 0; t2 < 2; t2++)
            #pragma unroll
            for (int r = 0; r < 16; r++) mx = fmaxf(mx, st[t2][r]);
        mx = fmaxf(mx, __shfl_xor(mx, 32));
        float mnew = fmaxf(m_st, mx);
        float alpha = __expf(m_st - mnew);
        float sum = 0.f;
        #pragma unroll
        for (int t2 = 0; t2 < 2; t2++)
            #pragma unroll
            for (int r = 0; r < 16; r++) {
                float p = __expf(st[t2][r] - mnew);
                st[t2][r] = p;
                sum += p;
            }
        sum += __shfl_xor(sum, 32);
        l_st = l_st * alpha + sum;
        m_st = mnew;

        #pragma unroll
        for (int t2 = 0; t2 < 2; t2++)
            #pragma unroll
            for (int g = 0; g < 4; g++) {
                bf16x4 pk = {(__bf16)st[t2][4 * g],     (__bf16)st[t2][4 * g + 1],
                             (__bf16)st[t2][4 * g + 2], (__bf16)st[t2][4 * g + 3]};
                int ch = (t2 * 4 + g) ^ (l31 & 7);
                *(bf16x4*)&Psw[l31 * 64 + ch * 8 + 4 * h] = pk;
            }
        #pragma unroll
        for (int dt = 0; dt < 4; dt++)
            #pragma unroll
            for (int r = 0; r < 16; r++) oacc[dt][r] *= alpha;

        #pragma unroll
        for (int kc = 0; kc < 4; kc++) {
            int chp = (kc * 2 + h) ^ (l31 & 7);
            bf16x8 bp = *(bf16x8*)&Psw[l31 * 64 + chp * 8];
            #pragma unroll
            for (int dt = 0; dt < 4; dt++) {
                int row = dt * 32 + l31;
                int cv = (kc * 2 + h) ^ (row & 7);
                bf16x8 av = *(bf16x8*)&Vts[row * 64 + cv * 8];
                oacc[dt] = MFMA32(av, bp, oacc[dt]);
            }
        }
    }

    __syncthreads();
    __bf16* Ob = (__bf16*)smem + wv * 4096;   // 32 x 128 (chunk ^= qr&15)
    float linv = 1.f / l_st;
    #pragma unroll
    for (int dt = 0; dt < 4; dt++)
        #pragma unroll
        for (int g = 0; g < 4; g++) {
            bf16x4 pk = {(__bf16)(oacc[dt][4 * g] * linv),
                         (__bf16)(oacc[dt][4 * g + 1] * linv),
                         (__bf16)(oacc[dt][4 * g + 2] * linv),
                         (__bf16)(oacc[dt][4 * g + 3] * linv)};
            int ch = (dt * 4 + g) ^ (l31 & 15);
            *(bf16x4*)&Ob[l31 * 128 + ch * 8 + 4 * h] = pk;
        }
    int bc = bch >> 3, h0 = bch & 7;
    #pragma unroll
    for (int i = 0; i < 8; i++) {
        int p = i * 64 + lane;
        int rr = p >> 4, cc = p & 15;
        int cs = cc ^ (rr & 15);
        bf16x8 v = *(bf16x8*)&Ob[rr * 128 + cs * 8];
        *(bf16x8*)&attnT[((size_t)bc * Ww + q0 + wv * 32 + rr) * BINS + h0 * HD + cc * 8] = v;
    }
}

// ---------------------------------------------------------------------------
// Launch. Workspace: 6 slots of NELEM bf16 = 100.66 MB.
//  U0 Wq_bf | U1 xT | U2 Wout_bf | U3 y(bf16) -> attnT | U4 vt | U5 qrot
// ---------------------------------------------------------------------------
extern "C" void kernel_launch(void* const* d_in, const int* in_sizes, int n_in,
                              void* d_out, int out_size, void* d_ws, size_t ws_size,
                              hipStream_t stream) {
    const float* x       = (const float*)d_in[0];
    const float* Wq_lin  = (const float*)d_in[1];
    const float* Wq_conv = (const float*)d_in[2];
    const float* bq_conv = (const float*)d_in[3];
    const float* Wout    = (const float*)d_in[4];
    float* out = (float*)d_out;

    __bf16* U = (__bf16*)d_ws;
    __bf16* Wq_bf   = U;
    __bf16* xT      = U + 1 * (size_t)NELEM;
    __bf16* Wout_bf = U + 2 * (size_t)NELEM;
    __bf16* y       = U + 3 * (size_t)NELEM;
    __bf16* vtb     = U + 4 * (size_t)NELEM;
    __bf16* qrot    = U + 5 * (size_t)NELEM;
    __bf16* attnT   = U + 3 * (size_t)NELEM;   // y dead after conv

    cast_bf16_2<<<dim3(NELEM / (8 * 256), 2), 256, 0, stream>>>(Wq_lin, Wout, Wq_bf, Wout_bf);
    transpose_cast_x<<<dim3(Ww / 64, BINS / 64, Bb * Cc_), 256, 0, stream>>>(x, xT);
    // 1. y = Wq_lin @ x  (bf16 out)
    gemm32<true><<<dim3(Ww / 128, BINS / 128, Bb * Cc_), 256, 0, stream>>>(Wq_bf, xT, y);
    // 2. vt = bf16(conv1x3(y) + bias)   (= V^T layout)
    conv1x3_reg<<<dim3(Bb * BINS * 64 / 256), 256, 0, stream>>>(y, Wq_conv, bq_conv, vtb);
    // 3. qrot = rotary(vt), transposed to [bch][p][d]
    rotary_transpose<<<dim3(Ww / 64, Bb * Cc_ * HEADS), 256, 0, stream>>>(vtb, qrot);
    // 4. attention -> attnT bf16 [bc][p][bins]
    attn32<<<dim3((Ww / 128) * 128), 256, 0, stream>>>(qrot, vtb, attnT);
    // 5. out = Wout @ attn  (f32 out)
    gemm32<false><<<dim3(Ww / 128, BINS / 128, Bb * Cc_), 256, 0, stream>>>(Wout_bf, attnT, out);
}

// Round 6
// 236.472 us; speedup vs baseline: 5.7839x; 1.0700x over previous
//
#include <hip/hip_runtime.h>
#include <cstddef>

// Problem constants
#define Bb 2
#define Cc_ 8
#define BINS 1024
#define Ww 512
#define HEADS 8
#define HD 128
#define NELEM (Bb*Cc_*BINS*Ww)   // 8388608

typedef __attribute__((ext_vector_type(8)))  __bf16 bf16x8;
typedef __attribute__((ext_vector_type(4)))  __bf16 bf16x4;
typedef __attribute__((ext_vector_type(4)))  float  f32x4;
typedef __attribute__((ext_vector_type(16))) float  f32x16;
#define MFMA32(a,b,c) __builtin_amdgcn_mfma_f32_32x32x16_bf16(a,b,c,0,0,0)

// async global->LDS: lane i's 16B lands at ldsbase + i*16; global addr is a
// per-lane gather, so we pre-swizzle by computing the SOURCE of each slot.
__device__ __forceinline__ void async16(const __bf16* g, __bf16* l) {
    __builtin_amdgcn_global_load_lds(
        (const __attribute__((address_space(1))) void*)g,
        (__attribute__((address_space(3))) void*)l, 16, 0, 0);
}

// ---------------------------------------------------------------------------
// Fused prep: cast Wq (blocks 0..4095), cast Wout (4096..8191),
// transpose-cast x -> xT [bc][w][i] (8192..10239).
// ---------------------------------------------------------------------------
__global__ void __launch_bounds__(256) prep(const float* __restrict__ Wq,
                                            const float* __restrict__ Wout,
                                            const float* __restrict__ x,
                                            __bf16* __restrict__ Wqb,
                                            __bf16* __restrict__ Woutb,
                                            __bf16* __restrict__ xT) {
    int bid = blockIdx.x;
    int t = threadIdx.x;
    if (bid < 8192) {
        const float* in = (bid < 4096) ? Wq : Wout;
        __bf16* out     = (bid < 4096) ? Wqb : Woutb;
        size_t i = ((size_t)(bid & 4095) * 256 + t) * 8;
        float4 a = *(const float4*)&in[i];
        float4 b = *(const float4*)&in[i + 4];
        bf16x8 o = {(__bf16)a.x, (__bf16)a.y, (__bf16)a.z, (__bf16)a.w,
                    (__bf16)b.x, (__bf16)b.y, (__bf16)b.z, (__bf16)b.w};
        *(bf16x8*)&out[i] = o;
        return;
    }
    int b2 = bid - 8192;                   // 0..2047
    int w0 = (b2 & 7) * 64;
    int i0 = ((b2 >> 3) & 15) * 64;
    int bc = b2 >> 7;
    const float* src = x + (size_t)bc * BINS * Ww;
    __bf16* dst = xT + (size_t)bc * Ww * BINS;
    __shared__ float T[64][65];
    #pragma unroll
    for (int pass = 0; pass < 4; pass++) {
        int idx = t + pass * 256;
        int il = idx >> 4, ch = idx & 15;
        float4 v = *(const float4*)&src[(size_t)(i0 + il) * Ww + w0 + ch * 4];
        T[il][ch * 4 + 0] = v.x; T[il][ch * 4 + 1] = v.y;
        T[il][ch * 4 + 2] = v.z; T[il][ch * 4 + 3] = v.w;
    }
    __syncthreads();
    #pragma unroll
    for (int pass = 0; pass < 2; pass++) {
        int idx = t + pass * 256;
        int wl = idx >> 3, ch = idx & 7;
        bf16x8 o;
        #pragma unroll
        for (int j = 0; j < 8; j++) o[j] = (__bf16)T[ch * 8 + j][wl];
        *(bf16x8*)&dst[(size_t)(w0 + wl) * BINS + i0 + ch * 8] = o;
    }
}

// ---------------------------------------------------------------------------
// bf16 GEMM, 32x32x16 MFMA. Y[bc][m][n] = sum_k A[c][m][k]*Bt[bc][n][k]
// 128x128 tile, BK=64 (16 iterations, half the barrier drains of BK=32),
// 4 waves each 64x64 (2x2 of 32x32). XOR-swizzled LDS (8-chunk rows) via
// gathered async16. Epilogue repacks C through LDS for coalesced stores.
// ---------------------------------------------------------------------------
template<bool BF16OUT>
__global__ void __launch_bounds__(256) gemm32(const __bf16* __restrict__ Wall,
                                              const __bf16* __restrict__ Bt,
                                              void* __restrict__ Yv) {
    int bc = blockIdx.z, c = bc & 7;
    const __bf16* A  = Wall + (size_t)c  * BINS * BINS;   // [m][k]
    const __bf16* Bm = Bt   + (size_t)bc * Ww * BINS;     // [n][k]
    int n0 = blockIdx.x * 128, m0 = blockIdx.y * 128;

    __shared__ __align__(16) char smem[32768];
    __bf16* Asm = (__bf16*)smem;            // 128 rows x 64 k (8 chunks of 16B)
    __bf16* Bsm = (__bf16*)(smem + 16384);

    int t = threadIdx.x, w = t >> 6, l = t & 63;
    int l31 = l & 31, h = l >> 5;
    int wm = w >> 1, wn = w & 1;

    // staging decode: slot p = j*256 + w*64 + l -> row p>>3, source chunk (p&7)^(row&7)
    int rowS[4], colS[4];
    #pragma unroll
    for (int j = 0; j < 4; j++) {
        int p = j * 256 + w * 64 + l;
        int r = p >> 3, cs = (p & 7) ^ (r & 7);
        rowS[j] = r; colS[j] = cs * 8;
    }

    f32x16 acc[2][2];
    #pragma unroll
    for (int a = 0; a < 2; a++)
        #pragma unroll
        for (int b = 0; b < 2; b++)
            #pragma unroll
            for (int r = 0; r < 16; r++) acc[a][b][r] = 0.f;

    for (int k0 = 0; k0 < BINS; k0 += 64) {
        __syncthreads();
        #pragma unroll
        for (int j = 0; j < 4; j++) {
            async16(A  + (size_t)(m0 + rowS[j]) * BINS + k0 + colS[j],
                    Asm + (j * 256 + w * 64) * 8);
            async16(Bm + (size_t)(n0 + rowS[j]) * BINS + k0 + colS[j],
                    Bsm + (j * 256 + w * 64) * 8);
        }
        __syncthreads();
        bf16x8 af[2][4], bfr[2][4];
        #pragma unroll
        for (int mt = 0; mt < 2; mt++)
            #pragma unroll
            for (int kc = 0; kc < 4; kc++) {
                int row = wm * 64 + mt * 32 + l31;
                int ch = (kc * 2 + h) ^ (row & 7);
                af[mt][kc] = *(bf16x8*)&Asm[row * 64 + ch * 8];
            }
        #pragma unroll
        for (int nt = 0; nt < 2; nt++)
            #pragma unroll
            for (int kc = 0; kc < 4; kc++) {
                int row = wn * 64 + nt * 32 + l31;
                int ch = (kc * 2 + h) ^ (row & 7);
                bfr[nt][kc] = *(bf16x8*)&Bsm[row * 64 + ch * 8];
            }
        #pragma unroll
        for (int kc = 0; kc < 4; kc++)
            #pragma unroll
            for (int mt = 0; mt < 2; mt++)
                #pragma unroll
                for (int nt = 0; nt < 2; nt++)
                    acc[mt][nt] = MFMA32(af[mt][kc], bfr[nt][kc], acc[mt][nt]);
    }

    // epilogue: C/D reg map row = (reg&3)+8*(reg>>2)+4*h, col = l31.
    // Repack through LDS -> coalesced wide stores.
    __syncthreads();
    if constexpr (BF16OUT) {
        __bf16* Ob = (__bf16*)smem;         // [128][128]
        __bf16* Cm = (__bf16*)Yv + (size_t)bc * BINS * Ww;
        #pragma unroll
        for (int mt = 0; mt < 2; mt++)
            #pragma unroll
            for (int nt = 0; nt < 2; nt++)
                #pragma unroll
                for (int reg = 0; reg < 16; reg++) {
                    int ml = wm * 64 + mt * 32 + (reg & 3) + 8 * (reg >> 2) + 4 * h;
                    int nl = wn * 64 + nt * 32 + l31;
                    Ob[ml * 128 + nl] = (__bf16)acc[mt][nt][reg];
                }
        __syncthreads();
        #pragma unroll
        for (int pass = 0; pass < 8; pass++) {
            int idx = t + pass * 256;        // 0..2047
            int row = idx >> 4, ch = idx & 15;
            *(bf16x8*)&Cm[(size_t)(m0 + row) * Ww + n0 + ch * 8] =
                *(bf16x8*)&Ob[row * 128 + ch * 8];
        }
    } else {
        float* Of = (float*)smem;           // [64][128] per half
        float* Cm = (float*)Yv + (size_t)bc * BINS * Ww;
        #pragma unroll
        for (int half = 0; half < 2; half++) {
            if (wm == half) {
                #pragma unroll
                for (int mt = 0; mt < 2; mt++)
                    #pragma unroll
                    for (int nt = 0; nt < 2; nt++)
                        #pragma unroll
                        for (int reg = 0; reg < 16; reg++) {
                            int ml = mt * 32 + (reg & 3) + 8 * (reg >> 2) + 4 * h;
                            int nl = wn * 64 + nt * 32 + l31;
                            Of[ml * 128 + nl] = acc[mt][nt][reg];
                        }
            }
            __syncthreads();
            #pragma unroll
            for (int pass = 0; pass < 8; pass++) {
                int idx = t + pass * 256;    // 0..2047
                int row = idx >> 5, c4 = idx & 31;
                *(float4*)&Cm[(size_t)(m0 + half * 64 + row) * Ww + n0 + c4 * 4] =
                    *(float4*)&Of[row * 128 + c4 * 4];
            }
            __syncthreads();
        }
    }
}

// ---------------------------------------------------------------------------
// cross-channel 1x3 conv + bias — register form, no LDS (unchanged from R5).
// ---------------------------------------------------------------------------
__global__ void __launch_bounds__(256) conv1x3_reg(const __bf16* __restrict__ y,
                                                   const float* __restrict__ Wc,
                                                   const float* __restrict__ bias,
                                                   __bf16* __restrict__ vt) {
    int tid = blockIdx.x * 256 + threadIdx.x;
    int wc = tid & 63;
    int h  = (tid >> 6) & 1023;
    int b  = tid >> 16;
    int w0 = wc * 8;

    float ym[8][8], yl[8], yr[8];
    #pragma unroll
    for (int ci = 0; ci < 8; ci++) {
        const __bf16* row = y + ((size_t)(b * 8 + ci) * BINS + h) * Ww;
        bf16x8 v = *(const bf16x8*)&row[w0];
        #pragma unroll
        for (int j = 0; j < 8; j++) ym[ci][j] = (float)v[j];
        yl[ci] = (w0 > 0)   ? (float)row[w0 - 1] : 0.f;
        yr[ci] = (w0 < 504) ? (float)row[w0 + 8] : 0.f;
    }
    #pragma unroll
    for (int co = 0; co < 8; co++) {
        float acc[8];
        float bv = bias[co];
        #pragma unroll
        for (int j = 0; j < 8; j++) acc[j] = bv;
        #pragma unroll
        for (int ci = 0; ci < 8; ci++) {
            float wa = Wc[(co * 8 + ci) * 3 + 0];
            float wb = Wc[(co * 8 + ci) * 3 + 1];
            float wcc = Wc[(co * 8 + ci) * 3 + 2];
            acc[0] += yl[ci] * wa;
            #pragma unroll
            for (int j = 1; j < 8; j++) acc[j] += ym[ci][j - 1] * wa;
            #pragma unroll
            for (int j = 0; j < 8; j++) acc[j] += ym[ci][j] * wb;
            #pragma unroll
            for (int j = 0; j < 7; j++) acc[j] += ym[ci][j + 1] * wcc;
            acc[7] += yr[ci] * wcc;
        }
        bf16x8 o;
        #pragma unroll
        for (int j = 0; j < 8; j++) o[j] = (__bf16)acc[j];
        *(bf16x8*)&vt[((size_t)(b * 8 + co) * BINS + h) * Ww + w0] = o;
    }
}

// ---------------------------------------------------------------------------
// rotary + transpose: vt bf16 [bch][d][p] -> qrot bf16 [bch][p][d] (unchanged)
// ---------------------------------------------------------------------------
__global__ void __launch_bounds__(256) rotary_transpose(const __bf16* __restrict__ vt,
                                                        __bf16* __restrict__ qrot) {
    int p0  = blockIdx.x * 64;
    int bch = blockIdx.y;
    int t = threadIdx.x;
    __shared__ float T[64 * 129];   // [p_local][d]

    const __bf16* src = vt + (size_t)bch * HD * Ww;
    for (int pass = 0; pass < 4; pass++) {
        int idx = t + pass * 256;
        int d = idx >> 3, ch = idx & 7;
        bf16x8 v = *(const bf16x8*)&src[(size_t)d * Ww + p0 + ch * 8];
        #pragma unroll
        for (int j = 0; j < 8; j++) T[(ch * 8 + j) * 129 + d] = (float)v[j];
    }
    __syncthreads();
    for (int pass = 0; pass < 4; pass++) {
        int idx = t + pass * 256;
        int p = idx >> 4, chunk = idx & 15;
        float pos = (float)(p0 + p);
        bf16x8 o;
        if (chunk < 8) {
            #pragma unroll
            for (int j = 0; j < 8; j += 2) {
                int d = chunk * 8 + j;
                int jj = d >> 1;
                float inv = __expf(-(2.0f * jj / 64.0f) * 9.210340371976184f);
                float sn, cs;
                __sincosf(pos * inv, &sn, &cs);
                float x1 = T[p * 129 + d];
                float x2 = T[p * 129 + d + 1];
                o[j]     = (__bf16)(x1 * cs - x2 * sn);
                o[j + 1] = (__bf16)(x2 * cs + x1 * sn);
            }
        } else {
            #pragma unroll
            for (int j = 0; j < 8; j++)
                o[j] = (__bf16)T[p * 129 + chunk * 8 + j];
        }
        *(bf16x8*)&qrot[((size_t)bch * Ww + p0 + p) * HD + chunk * 8] = o;
    }
}

// ---------------------------------------------------------------------------
// Flash attention, 32x32x16 MFMA, S^T orientation (unchanged from R5).
// ---------------------------------------------------------------------------
__global__ void __launch_bounds__(256, 2) attn32(const __bf16* __restrict__ qrot,
                                                 const __bf16* __restrict__ vt,
                                                 __bf16* __restrict__ attnT) {
    int bid = blockIdx.x;
    int bch = bid & 127, q0 = (bid >> 7) * 128;
    int t = threadIdx.x, wv = t >> 6, lane = t & 63;
    int l31 = lane & 31, h = lane >> 5;

    __shared__ __align__(16) char smem[49152];
    __bf16* Ks  = (__bf16*)smem;                        // 64 kpos x 128 d   (chunk ^= r&15)
    __bf16* Vts = (__bf16*)(smem + 16384);              // 128 d  x 64 kpos  (chunk ^= r&7)
    __bf16* Psw = (__bf16*)(smem + 32768) + wv * 2048;  // 32 qr x 64 kpos, per wave

    const __bf16* qb = qrot + (size_t)bch * Ww * HD;   // [p][d]
    const __bf16* vb = vt   + (size_t)bch * HD * Ww;   // [d][p]

    int qrow = q0 + wv * 32 + l31;
    bf16x8 qf[8];
    #pragma unroll
    for (int c = 0; c < 8; c++) {
        bf16x8 v = *(const bf16x8*)&qb[(size_t)qrow * HD + c * 16 + h * 8];
        #pragma unroll
        for (int j = 0; j < 8; j++) v[j] = (__bf16)((float)v[j] * 0.03125f);
        qf[c] = v;
    }

    f32x16 oacc[4];
    #pragma unroll
    for (int dt = 0; dt < 4; dt++)
        #pragma unroll
        for (int r = 0; r < 16; r++) oacc[dt][r] = 0.f;
    float m_st = -1e30f, l_st = 0.f;

    for (int kt = 0; kt < 8; kt++) {
        int k0 = kt * 64;
        __syncthreads();
        #pragma unroll
        for (int i = 0; i < 4; i++) {
            int p = wv * 256 + i * 64 + lane;
            int r  = p >> 4, cs  = ((p & 15) ^ (r & 15)) * 8;
            async16(qb + (size_t)(k0 + r) * HD + cs, Ks + (wv * 256 + i * 64) * 8);
            int r2 = p >> 3, cs2 = ((p & 7) ^ (r2 & 7)) * 8;
            async16(vb + (size_t)r2 * Ww + k0 + cs2, Vts + (wv * 256 + i * 64) * 8);
        }
        __syncthreads();

        f32x16 st[2];
        #pragma unroll
        for (int t2 = 0; t2 < 2; t2++)
            #pragma unroll
            for (int r = 0; r < 16; r++) st[t2][r] = 0.f;
        #pragma unroll
        for (int c = 0; c < 8; c++)
            #pragma unroll
            for (int t2 = 0; t2 < 2; t2++) {
                int row = t2 * 32 + l31;
                int ch = (c * 2 + h) ^ (row & 15);
                bf16x8 ak = *(bf16x8*)&Ks[row * 128 + ch * 8];
                st[t2] = MFMA32(ak, qf[c], st[t2]);
            }

        float mx = -1e30f;
        #pragma unroll
        for (int t2 = 0; t2 < 2; t2++)
            #pragma unroll
            for (int r = 0; r < 16; r++) mx = fmaxf(mx, st[t2][r]);
        mx = fmaxf(mx, __shfl_xor(mx, 32));
        float mnew = fmaxf(m_st, mx);
        float alpha = __expf(m_st - mnew);
        float sum = 0.f;
        #pragma unroll
        for (int t2 = 0; t2 < 2; t2++)
            #pragma unroll
            for (int r = 0; r < 16; r++) {
                float p = __expf(st[t2][r] - mnew);
                st[t2][r] = p;
                sum += p;
            }
        sum += __shfl_xor(sum, 32);
        l_st = l_st * alpha + sum;
        m_st = mnew;

        #pragma unroll
        for (int t2 = 0; t2 < 2; t2++)
            #pragma unroll
            for (int g = 0; g < 4; g++) {
                bf16x4 pk = {(__bf16)st[t2][4 * g],     (__bf16)st[t2][4 * g + 1],
                             (__bf16)st[t2][4 * g + 2], (__bf16)st[t2][4 * g + 3]};
                int ch = (t2 * 4 + g) ^ (l31 & 7);
                *(bf16x4*)&Psw[l31 * 64 + ch * 8 + 4 * h] = pk;
            }
        #pragma unroll
        for (int dt = 0; dt < 4; dt++)
            #pragma unroll
            for (int r = 0; r < 16; r++) oacc[dt][r] *= alpha;

        #pragma unroll
        for (int kc = 0; kc < 4; kc++) {
            int chp = (kc * 2 + h) ^ (l31 & 7);
            bf16x8 bp = *(bf16x8*)&Psw[l31 * 64 + chp * 8];
            #pragma unroll
            for (int dt = 0; dt < 4; dt++) {
                int row = dt * 32 + l31;
                int cv = (kc * 2 + h) ^ (row & 7);
                bf16x8 av = *(bf16x8*)&Vts[row * 64 + cv * 8];
                oacc[dt] = MFMA32(av, bp, oacc[dt]);
            }
        }
    }

    __syncthreads();
    __bf16* Ob = (__bf16*)smem + wv * 4096;   // 32 x 128 (chunk ^= qr&15)
    float linv = 1.f / l_st;
    #pragma unroll
    for (int dt = 0; dt < 4; dt++)
        #pragma unroll
        for (int g = 0; g < 4; g++) {
            bf16x4 pk = {(__bf16)(oacc[dt][4 * g] * linv),
                         (__bf16)(oacc[dt][4 * g + 1] * linv),
                         (__bf16)(oacc[dt][4 * g + 2] * linv),
                         (__bf16)(oacc[dt][4 * g + 3] * linv)};
            int ch = (dt * 4 + g) ^ (l31 & 15);
            *(bf16x4*)&Ob[l31 * 128 + ch * 8 + 4 * h] = pk;
        }
    int bc = bch >> 3, h0 = bch & 7;
    #pragma unroll
    for (int i = 0; i < 8; i++) {
        int p = i * 64 + lane;
        int rr = p >> 4, cc = p & 15;
        int cs = cc ^ (rr & 15);
        bf16x8 v = *(bf16x8*)&Ob[rr * 128 + cs * 8];
        *(bf16x8*)&attnT[((size_t)bc * Ww + q0 + wv * 32 + rr) * BINS + h0 * HD + cc * 8] = v;
    }
}

// ---------------------------------------------------------------------------
// Launch. Workspace: 6 slots of NELEM bf16 = 100.66 MB.
//  U0 Wq_bf | U1 xT | U2 Wout_bf | U3 y(bf16) -> attnT | U4 vt | U5 qrot
// ---------------------------------------------------------------------------
extern "C" void kernel_launch(void* const* d_in, const int* in_sizes, int n_in,
                              void* d_out, int out_size, void* d_ws, size_t ws_size,
                              hipStream_t stream) {
    const float* x       = (const float*)d_in[0];
    const float* Wq_lin  = (const float*)d_in[1];
    const float* Wq_conv = (const float*)d_in[2];
    const float* bq_conv = (const float*)d_in[3];
    const float* Wout    = (const float*)d_in[4];
    float* out = (float*)d_out;

    __bf16* U = (__bf16*)d_ws;
    __bf16* Wq_bf   = U;
    __bf16* xT      = U + 1 * (size_t)NELEM;
    __bf16* Wout_bf = U + 2 * (size_t)NELEM;
    __bf16* y       = U + 3 * (size_t)NELEM;
    __bf16* vtb     = U + 4 * (size_t)NELEM;
    __bf16* qrot    = U + 5 * (size_t)NELEM;
    __bf16* attnT   = U + 3 * (size_t)NELEM;   // y dead after conv

    // 0. fused prep: both weight casts + x transpose-cast
    prep<<<dim3(8192 + 2048), 256, 0, stream>>>(Wq_lin, Wout, x, Wq_bf, Wout_bf, xT);
    // 1. y = Wq_lin @ x  (bf16 out)
    gemm32<true><<<dim3(Ww / 128, BINS / 128, Bb * Cc_), 256, 0, stream>>>(Wq_bf, xT, y);
    // 2. vt = bf16(conv1x3(y) + bias)   (= V^T layout)
    conv1x3_reg<<<dim3(Bb * BINS * 64 / 256), 256, 0, stream>>>(y, Wq_conv, bq_conv, vtb);
    // 3. qrot = rotary(vt), transposed to [bch][p][d]
    rotary_transpose<<<dim3(Ww / 64, Bb * Cc_ * HEADS), 256, 0, stream>>>(vtb, qrot);
    // 4. attention -> attnT bf16 [bc][p][bins]
    attn32<<<dim3((Ww / 128) * 128), 256, 0, stream>>>(qrot, vtb, attnT);
    // 5. out = Wout @ attn  (f32 out)
    gemm32<false><<<dim3(Ww / 128, BINS / 128, Bb * Cc_), 256, 0, stream>>>(Wout_bf, attnT, out);
}